// Round 8
// baseline (365.138 us; speedup 1.0000x reference)
//
#include <hip/hip_runtime.h>
#include <hip/hip_bf16.h>

#define NEGV -1e10f
#define NEG_INF -3.402823466e38f

typedef __attribute__((ext_vector_type(8))) short short8;
typedef __attribute__((ext_vector_type(4))) float floatx4;

__device__ inline float bf2f(unsigned short u) {
    union { unsigned int i; float f; } c; c.i = ((unsigned int)u) << 16; return c.f;
}
__device__ inline unsigned short f2b(float f) {
    __hip_bfloat16 h = __float2bfloat16(f);
    return *reinterpret_cast<unsigned short*>(&h);
}
// product of two packed bf16 pairs -> packed bf16 pair (RNE)
__device__ inline unsigned int mul2bf(unsigned int x, unsigned int y) {
    union { unsigned int i; float f; } xl, xh, yl, yh;
    xl.i = x << 16; xh.i = x & 0xffff0000u;
    yl.i = y << 16; yh.i = y & 0xffff0000u;
    unsigned int lo = f2b(xl.f * yl.f);
    unsigned int hi = f2b(xh.f * yh.f);
    return lo | (hi << 16);
}

#define GLL16(g, l) __builtin_amdgcn_global_load_lds( \
    (const __attribute__((address_space(1))) void*)(g), \
    (__attribute__((address_space(3))) void*)(l), 16, 0, 0)

// ---------------- KPREP: fused transposes + cont->bf16 + zero-inits ----------------
__device__ void transpose_tile(const float* __restrict__ in, int ldin, int krows,
                               unsigned short* __restrict__ out, int ldout,
                               int ktile, int ntile, unsigned short (*L)[66]) {
    int t = threadIdx.x;
    int kt = ktile * 64, nt = ntile * 64;
    int nl = t & 63, g = t >> 6;
#pragma unroll
    for (int i = 0; i < 16; ++i) {
        int kl = g * 16 + i;
        int k = kt + kl;
        float v = (k < krows) ? in[(size_t)k * ldin + nt + nl] : 0.f;
        L[kl][nl] = f2b(v);
    }
    __syncthreads();
    int kl2 = t & 63;
#pragma unroll
    for (int i = 0; i < 16; ++i) {
        int nl2 = g * 16 + i;
        out[(size_t)(nt + nl2) * ldout + kt + kl2] = L[kl2][nl2];
    }
}

__global__ __launch_bounds__(256) void kprep(
    const float* __restrict__ pw_w1, const float* __restrict__ pw_w2,
    const float* __restrict__ aw1, const float* __restrict__ cont,
    unsigned short* __restrict__ w1cT, unsigned short* __restrict__ w1aT,
    unsigned short* __restrict__ w1bT, unsigned short* __restrict__ w2T,
    unsigned short* __restrict__ aw1T, unsigned short* __restrict__ contb,
    float* __restrict__ ts, float* __restrict__ scores, float* __restrict__ attall,
    float* __restrict__ a, float* __restrict__ b) {
    __shared__ unsigned short L[64][66];
    int bid = blockIdx.x;
    int tid = threadIdx.x;
    if (bid < 592) {
        transpose_tile(pw_w1 + (size_t)2 * 2324 * 1024, 1024, 2324, w1cT, 2368,
                       bid % 37, bid / 37, L);
    } else if (bid < 1184) {
        int r = bid - 592;
        transpose_tile(pw_w1, 1024, 2324, w1aT, 2368, r % 37, r / 37, L);
    } else if (bid < 1776) {
        int r = bid - 1184;
        transpose_tile(pw_w1 + (size_t)2324 * 1024, 1024, 2324, w1bT, 2368, r % 37, r / 37, L);
    } else if (bid < 2032) {
        int r = bid - 1776;
        transpose_tile(pw_w2, 1024, 1024, w2T, 1024, r % 16, r / 16, L);
    } else if (bid < 2224) {
        int r = bid - 2032;
        transpose_tile(aw1, 1024, 768, aw1T, 768, r % 12, r / 12, L);
    } else if (bid < 6064) {
        int i = (bid - 2224) * 256 + tid;
        contb[i] = f2b(cont[i]);
    } else if (bid < 8368) {
        int i = (bid - 6064) * 256 + tid;
        attall[i] = 0.f;
        if (i < 16384) ts[i] = 0.f;
        if (i < 1280) scores[i] = 0.f;
    } else {
        int i = (bid - 8368) * 256 + tid;   // < 131072
        a[i] = 0.f;
        b[i] = 0.f;
    }
}

// ---------------- KMIDA: kscore (80 blocks) + k3a (96 blocks) merged ----------------
__global__ __launch_bounds__(256) void kmidA(
    const unsigned short* __restrict__ contb, const unsigned short* __restrict__ aw1T,
    const float* __restrict__ ab1, const float* __restrict__ aw2,
    float* __restrict__ scores,
    const float* __restrict__ doc, const float* __restrict__ img,
    float* __restrict__ attall) {
    __shared__ __align__(16) unsigned short Ash[128 * 32];
    __shared__ __align__(16) unsigned short Bsh[128 * 32];
    __shared__ float As[32][132];
    __shared__ float Bs[32][100];
    int bid = blockIdx.x;
    int tid = threadIdx.x;

    if (bid < 80) {
        // ---- kscore: scores[m] += sum_n relu(contb@aw1T + ab1)[m,n]*aw2[n] ----
        int m0 = (bid >> 3) * 128;
        int col0 = (bid & 7) * 128;
        int lane = tid & 63, wave = tid >> 6;
        int wm = wave >> 1, wn = wave & 1;
        int q = lane >> 4, l15 = lane & 15;

        floatx4 acc[4][4];
#pragma unroll
        for (int i = 0; i < 4; ++i)
#pragma unroll
            for (int j = 0; j < 4; ++j) acc[i][j] = (floatx4){0.f, 0.f, 0.f, 0.f};

        int ci0 = wave * 2, ci1 = wave * 2 + 1;
        int p = lane & 3;
        int r0 = ci0 * 16 + (lane >> 2), r1 = ci1 * 16 + (lane >> 2);
        int c0s = p ^ ((r0 >> 1) & 3), c1s = p ^ ((r1 >> 1) & 3);
        const char* gA0 = (const char*)(contb + (size_t)(m0 + r0) * 768) + c0s * 16;
        const char* gA1 = (const char*)(contb + (size_t)(m0 + r1) * 768) + c1s * 16;
        const char* gB0 = (const char*)(aw1T + (size_t)(col0 + r0) * 768) + c0s * 16;
        const char* gB1 = (const char*)(aw1T + (size_t)(col0 + r1) * 768) + c1s * 16;
        unsigned short* lA0 = Ash + ci0 * 512;
        unsigned short* lA1 = Ash + ci1 * 512;
        unsigned short* lB0 = Bsh + ci0 * 512;
        unsigned short* lB1 = Bsh + ci1 * 512;

        for (int kt = 0; kt < 24; ++kt) {
            __syncthreads();
            GLL16(gA0, lA0);
            GLL16(gA1, lA1);
            GLL16(gB0, lB0);
            GLL16(gB1, lB1);
            gA0 += 64; gA1 += 64; gB0 += 64; gB1 += 64;
            __syncthreads();
            short8 af[4], bfv[4];
#pragma unroll
            for (int i = 0; i < 4; ++i) {
                int rA = wm * 64 + i * 16 + l15;
                af[i] = *(const short8*)(Ash + rA * 32 + (q ^ ((rA >> 1) & 3)) * 8);
            }
#pragma unroll
            for (int j = 0; j < 4; ++j) {
                int rB = wn * 64 + j * 16 + l15;
                bfv[j] = *(const short8*)(Bsh + rB * 32 + (q ^ ((rB >> 1) & 3)) * 8);
            }
#pragma unroll
            for (int i = 0; i < 4; ++i)
#pragma unroll
                for (int j = 0; j < 4; ++j)
                    acc[i][j] = __builtin_amdgcn_mfma_f32_16x16x32_bf16(af[i], bfv[j], acc[i][j], 0, 0, 0);
        }

        float b1v[4], w2v[4];
        int nj[4];
#pragma unroll
        for (int j = 0; j < 4; ++j) {
            nj[j] = col0 + wn * 64 + j * 16 + l15;
            b1v[j] = ab1[nj[j]];
            w2v[j] = aw2[nj[j]];
        }
#pragma unroll
        for (int i = 0; i < 4; ++i) {
#pragma unroll
            for (int reg = 0; reg < 4; ++reg) {
                float s = 0.f;
#pragma unroll
                for (int j = 0; j < 4; ++j)
                    s += fmaxf(acc[i][j][reg] + b1v[j], 0.f) * w2v[j];
                s += __shfl_down(s, 8, 16);
                s += __shfl_down(s, 4, 16);
                s += __shfl_down(s, 2, 16);
                s += __shfl_down(s, 1, 16);
                if (l15 == 0)
                    atomicAdd(&scores[m0 + wm * 64 + i * 16 + q * 4 + reg], s);
            }
        }
    } else {
        // ---- k3a: att_all[512][288] += doc @ img^T (K-chunk) ----
        int r = bid - 80;
        int n0 = (r % 3) * 96;
        int m0 = ((r / 3) & 3) * 128;
        int k0base = (r / 12) * 128;
        int tx = tid & 15, ty = tid >> 4;
        float acc[8][6];
#pragma unroll
        for (int rr = 0; rr < 8; ++rr)
#pragma unroll
            for (int c = 0; c < 6; ++c) acc[rr][c] = 0.f;

        for (int kc = 0; kc < 4; ++kc) {
            int k0 = k0base + kc * 32;
            __syncthreads();
#pragma unroll
            for (int p2 = 0; p2 < 4; ++p2) {
                int f = tid + 256 * p2;
                int mm = f >> 3, kq = (f & 7) * 4;
                float4 v = *(const float4*)&doc[(size_t)(m0 + mm) * 1024 + k0 + kq];
                As[kq + 0][mm] = v.x; As[kq + 1][mm] = v.y;
                As[kq + 2][mm] = v.z; As[kq + 3][mm] = v.w;
            }
#pragma unroll
            for (int p2 = 0; p2 < 3; ++p2) {
                int f = tid + 256 * p2;
                int nn = f >> 3, kq = (f & 7) * 4;
                float4 v = *(const float4*)&img[(size_t)(n0 + nn) * 1024 + k0 + kq];
                Bs[kq + 0][nn] = v.x; Bs[kq + 1][nn] = v.y;
                Bs[kq + 2][nn] = v.z; Bs[kq + 3][nn] = v.w;
            }
            __syncthreads();
#pragma unroll 4
            for (int k = 0; k < 32; ++k) {
                float4 a0 = *(const float4*)&As[k][ty * 8];
                float4 a1 = *(const float4*)&As[k][ty * 8 + 4];
                float2 b0 = *(const float2*)&Bs[k][tx * 6];
                float2 b1 = *(const float2*)&Bs[k][tx * 6 + 2];
                float2 b2 = *(const float2*)&Bs[k][tx * 6 + 4];
                float ar[8] = {a0.x, a0.y, a0.z, a0.w, a1.x, a1.y, a1.z, a1.w};
                float br[6] = {b0.x, b0.y, b1.x, b1.y, b2.x, b2.y};
#pragma unroll
                for (int rr = 0; rr < 8; ++rr)
#pragma unroll
                    for (int c = 0; c < 6; ++c) acc[rr][c] = fmaf(ar[rr], br[c], acc[rr][c]);
            }
        }
#pragma unroll
        for (int rr = 0; rr < 8; ++rr)
#pragma unroll
            for (int c = 0; c < 6; ++c)
                atomicAdd(&attall[(size_t)(m0 + ty * 8 + rr) * 288 + n0 + tx * 6 + c], acc[rr][c]);
    }
}

// ---------------- K2: softmax over span tokens, assemble bf16 span embeddings -------------
__global__ __launch_bounds__(256) void k2_assemble(
    const float* __restrict__ se, const float* __restrict__ cont,
    const int* __restrict__ width, const float* __restrict__ scores,
    const float* __restrict__ ab2, const float* __restrict__ wemb,
    unsigned short* __restrict__ sb) {
    int nm = blockIdx.x, tid = threadIdx.x;
    int wd = width[nm];
    float ab2v = ab2[0];
    float sc[10];
    float m = NEG_INF;
#pragma unroll
    for (int t = 0; t < 10; ++t) {
        float s = scores[nm * 10 + t] + ab2v;
        sc[t] = (t < wd) ? s : NEGV;
        m = fmaxf(m, sc[t]);
    }
    float sum = 0.f;
#pragma unroll
    for (int t = 0; t < 10; ++t) { sc[t] = expf(sc[t] - m); sum += sc[t]; }
    float inv = 1.f / sum;
#pragma unroll
    for (int t = 0; t < 10; ++t) sc[t] *= inv;
    const float* cbase = cont + (size_t)nm * 7680;
    unsigned short* srow = sb + (size_t)nm * 2368;
    for (int d = tid; d < 768; d += 256) {
        float acc = 0.f;
#pragma unroll
        for (int t = 0; t < 10; ++t) acc = fmaf(sc[t], cbase[t * 768 + d], acc);
        srow[1536 + d] = f2b(acc);
    }
    for (int idx = tid; idx < 1536; idx += 256) srow[idx] = f2b(se[(size_t)nm * 1536 + idx]);
    if (tid < 20) srow[2304 + tid] = f2b(wemb[min(wd, 4) * 20 + tid]);
    if (tid >= 20 && tid < 64) srow[2304 + tid] = 0;
}

// ---------------- KMIDB: kP2 (16384) + k4 K-split (128) + k3b (64) merged ----------------
__global__ __launch_bounds__(256) void kmidB(
    const unsigned short* __restrict__ sb, unsigned short* __restrict__ P, int doP,
    const unsigned short* __restrict__ w1aT, const unsigned short* __restrict__ w1bT,
    float* __restrict__ aout, float* __restrict__ bout,
    const float* __restrict__ attall, const float* __restrict__ tm,
    const float* __restrict__ im, float* __restrict__ Sg) {
    __shared__ __align__(16) unsigned short Ash[128 * 32];
    __shared__ __align__(16) unsigned short Bsh[128 * 32];
    __shared__ float att[64][37];
    __shared__ float tmv[64], imv[36];
    __shared__ float s1sh;
    int bid = blockIdx.x;
    int tid = threadIdx.x;

    if (bid < 16384) {
        // ---- kP2: canonical products ----
        if (!doP) return;
        int w = bid & 127, u = bid >> 7;
        if (u > w) return;
        const uint4* su = (const uint4*)(sb + (size_t)u * 2368);
        const uint4* sw = (const uint4*)(sb + (size_t)w * 2368);
        uint4* out = (uint4*)(P + ((size_t)u * 128 + w) * 2368);
        for (int i = tid; i < 296; i += 256) {
            uint4 a = su[i], b = sw[i];
            uint4 r;
            r.x = mul2bf(a.x, b.x); r.y = mul2bf(a.y, b.y);
            r.z = mul2bf(a.z, b.z); r.w = mul2bf(a.w, b.w);
            out[i] = r;
        }
    } else if (bid < 16512) {
        // ---- k4 K-split: a += sb@w1aT[kz], b += sb@w1bT[kz] (atomic fp32) ----
        int r = bid - 16384;
        int col0 = (r & 7) * 128;
        int half = (r >> 3) & 1;
        int kz = r >> 4;                          // [0,8)
        int kt0 = (74 * kz) / 8, kt1 = (74 * (kz + 1)) / 8;
        const unsigned short* wT = half ? w1bT : w1aT;
        float* outp = half ? bout : aout;
        int lane = tid & 63, wave = tid >> 6;
        int wm = wave >> 1, wn = wave & 1;
        int q = lane >> 4, l15 = lane & 15;

        floatx4 acc[4][4];
#pragma unroll
        for (int i = 0; i < 4; ++i)
#pragma unroll
            for (int j = 0; j < 4; ++j) acc[i][j] = (floatx4){0.f, 0.f, 0.f, 0.f};

        int ci0 = wave * 2, ci1 = wave * 2 + 1;
        int p = lane & 3;
        int r0 = ci0 * 16 + (lane >> 2), r1 = ci1 * 16 + (lane >> 2);
        int c0s = p ^ ((r0 >> 1) & 3), c1s = p ^ ((r1 >> 1) & 3);
        const char* gA0 = (const char*)(sb + (size_t)r0 * 2368) + c0s * 16 + kt0 * 64;
        const char* gA1 = (const char*)(sb + (size_t)r1 * 2368) + c1s * 16 + kt0 * 64;
        const char* gB0 = (const char*)(wT + (size_t)(col0 + r0) * 2368) + c0s * 16 + kt0 * 64;
        const char* gB1 = (const char*)(wT + (size_t)(col0 + r1) * 2368) + c1s * 16 + kt0 * 64;
        unsigned short* lA0 = Ash + ci0 * 512;
        unsigned short* lA1 = Ash + ci1 * 512;
        unsigned short* lB0 = Bsh + ci0 * 512;
        unsigned short* lB1 = Bsh + ci1 * 512;

        for (int kt = kt0; kt < kt1; ++kt) {
            __syncthreads();
            GLL16(gA0, lA0);
            GLL16(gA1, lA1);
            GLL16(gB0, lB0);
            GLL16(gB1, lB1);
            gA0 += 64; gA1 += 64; gB0 += 64; gB1 += 64;
            __syncthreads();
            short8 af[4], bfv[4];
#pragma unroll
            for (int i = 0; i < 4; ++i) {
                int rA = wm * 64 + i * 16 + l15;
                af[i] = *(const short8*)(Ash + rA * 32 + (q ^ ((rA >> 1) & 3)) * 8);
            }
#pragma unroll
            for (int j = 0; j < 4; ++j) {
                int rB = wn * 64 + j * 16 + l15;
                bfv[j] = *(const short8*)(Bsh + rB * 32 + (q ^ ((rB >> 1) & 3)) * 8);
            }
#pragma unroll
            for (int i = 0; i < 4; ++i)
#pragma unroll
                for (int j = 0; j < 4; ++j)
                    acc[i][j] = __builtin_amdgcn_mfma_f32_16x16x32_bf16(af[i], bfv[j], acc[i][j], 0, 0, 0);
        }

        int nj[4];
#pragma unroll
        for (int j = 0; j < 4; ++j) nj[j] = col0 + wn * 64 + j * 16 + l15;
#pragma unroll
        for (int i = 0; i < 4; ++i) {
#pragma unroll
            for (int reg = 0; reg < 4; ++reg) {
                int row = wm * 64 + i * 16 + q * 4 + reg;
#pragma unroll
                for (int j = 0; j < 4; ++j)
                    atomicAdd(&outp[(size_t)row * 1024 + nj[j]], acc[i][j][reg]);
            }
        }
    } else {
        // ---- k3b: per (s,v) mask + two softmax-reductions -> Sg ----
        int r2 = bid - 16512;
        int s = r2 >> 3, v = r2 & 7;
        if (tid < 64) tmv[tid] = tm[s * 64 + tid];
        if (tid >= 64 && tid < 100) imv[tid - 64] = im[v * 36 + (tid - 64)];
        __syncthreads();
        for (int idx = tid; idx < 2304; idx += 256) {
            int i = idx / 36, j = idx - i * 36;
            float raw = attall[(size_t)(s * 64 + i) * 288 + v * 36 + j];
            float x = raw * tmv[i] * imv[j];
            att[i][j] = (x != 0.f) ? x : NEGV;
        }
        __syncthreads();
        float part = 0.f;
        if (tid < 64) {
            int i = tid;
            float mx = NEG_INF;
            for (int j = 0; j < 36; ++j) mx = fmaxf(mx, att[i][j] * imv[j]);
            float sum = 0.f;
            for (int j = 0; j < 36; ++j) sum += expf(att[i][j] * imv[j] - mx);
            float invs = 1.f / sum;
            for (int j = 0; j < 36; ++j) {
                float aw = expf(att[i][j] * imv[j] - mx) * invs * (tmv[i] * imv[j]);
                part += aw * att[i][j];
            }
            for (int off = 32; off > 0; off >>= 1) part += __shfl_down(part, off);
            if (tid == 0) s1sh = part;
        }
        __syncthreads();
        if (tid < 64) {
            float part2 = 0.f;
            if (tid < 36) {
                int j = tid;
                float mx = NEG_INF;
                for (int i = 0; i < 64; ++i) mx = fmaxf(mx, att[i][j]);
                float sum = 0.f;
                for (int i = 0; i < 64; ++i) sum += expf(att[i][j] - mx);
                float invs = 1.f / sum;
                for (int i = 0; i < 64; ++i) {
                    float aw = expf(att[i][j] - mx) * invs * (tmv[i] * imv[j]);
                    part2 += aw * att[i][j];
                }
            }
            for (int off = 32; off > 0; off >>= 1) part2 += __shfl_down(part2, off);
            if (tid == 0) Sg[s * 8 + v] = s1sh + part2;
        }
    }
}

// ---------------- K5_SYM (MFMA, symmetric pair-tiles, XCD-swizzled, BK=64) ---------------
// Two consecutive 128x32 LDS sub-tiles per matrix per iter: same row layout and XOR
// swizzle as the proven BK=32 version (zero conflicts), half the barriers.
__global__ __launch_bounds__(256) void k5_sym(
    const unsigned short* __restrict__ P, const unsigned short* __restrict__ wT,
    const float* __restrict__ a, const float* __restrict__ b,
    const float* __restrict__ b1, unsigned short* __restrict__ h) {
    __shared__ __align__(16) unsigned short Ash[128 * 64];
    __shared__ __align__(16) unsigned short Bsh[128 * 64];
    int tid = threadIdx.x;
    int bid = blockIdx.x;
    int r8 = bid & 7, t = bid >> 3;
    int c = t & 7, pt = r8 + 8 * (t >> 3);
    const int offs[9] = {0, 16, 30, 42, 52, 60, 66, 70, 72};
    int ut = 0;
#pragma unroll
    for (int k = 1; k < 8; ++k) if (pt >= offs[k]) ut = k;
    int wt = 2 * ut + (pt - offs[ut]);
    int col0 = c * 128;

    int lane = tid & 63, wave = tid >> 6;
    int wm = wave >> 1, wn = wave & 1;
    int q = lane >> 4, l15 = lane & 15;

    floatx4 acc[4][4];
#pragma unroll
    for (int i = 0; i < 4; ++i)
#pragma unroll
        for (int j = 0; j < 4; ++j) acc[i][j] = (floatx4){0.f, 0.f, 0.f, 0.f};

    int ci0 = wave * 2, ci1 = wave * 2 + 1;
    int p = lane & 3;
    int r0 = ci0 * 16 + (lane >> 2), r1 = ci1 * 16 + (lane >> 2);
    int c0s = p ^ ((r0 >> 1) & 3), c1s = p ^ ((r1 >> 1) & 3);
    size_t prow0 = (size_t)(ut * 16 + (r0 >> 3)) * 128 + (wt * 8 + (r0 & 7));
    size_t prow1 = (size_t)(ut * 16 + (r1 >> 3)) * 128 + (wt * 8 + (r1 & 7));
    const char* gA0 = (const char*)(P + prow0 * 2368) + c0s * 16;
    const char* gA1 = (const char*)(P + prow1 * 2368) + c1s * 16;
    const char* gB0 = (const char*)(wT + (size_t)(col0 + r0) * 2368) + c0s * 16;
    const char* gB1 = (const char*)(wT + (size_t)(col0 + r1) * 2368) + c1s * 16;
    unsigned short* lA0 = Ash + ci0 * 512;
    unsigned short* lA1 = Ash + ci1 * 512;
    unsigned short* lB0 = Bsh + ci0 * 512;
    unsigned short* lB1 = Bsh + ci1 * 512;

    for (int kt = 0; kt < 37; ++kt) {
        __syncthreads();
        GLL16(gA0, lA0);
        GLL16(gA0 + 64, lA0 + 4096);
        GLL16(gA1, lA1);
        GLL16(gA1 + 64, lA1 + 4096);
        GLL16(gB0, lB0);
        GLL16(gB0 + 64, lB0 + 4096);
        GLL16(gB1, lB1);
        GLL16(gB1 + 64, lB1 + 4096);
        gA0 += 128; gA1 += 128; gB0 += 128; gB1 += 128;
        __syncthreads();
#pragma unroll
        for (int st = 0; st < 2; ++st) {
            const unsigned short* Asub = Ash + st * 4096;
            const unsigned short* Bsub = Bsh + st * 4096;
            short8 af[4], bfv[4];
#pragma unroll
            for (int i = 0; i < 4; ++i) {
                int rA = wm * 64 + i * 16 + l15;
                af[i] = *(const short8*)(Asub + rA * 32 + (q ^ ((rA >> 1) & 3)) * 8);
            }
#pragma unroll
            for (int j = 0; j < 4; ++j) {
                int rB = wn * 64 + j * 16 + l15;
                bfv[j] = *(const short8*)(Bsub + rB * 32 + (q ^ ((rB >> 1) & 3)) * 8);
            }
#pragma unroll
            for (int i = 0; i < 4; ++i)
#pragma unroll
                for (int j = 0; j < 4; ++j)
                    acc[i][j] = __builtin_amdgcn_mfma_f32_16x16x32_bf16(af[i], bfv[j], acc[i][j], 0, 0, 0);
        }
    }

    float b1v[4];
    int nj[4];
#pragma unroll
    for (int j = 0; j < 4; ++j) {
        nj[j] = col0 + wn * 64 + j * 16 + l15;
        b1v[j] = b1[nj[j]];
    }
#pragma unroll
    for (int i = 0; i < 4; ++i) {
#pragma unroll
        for (int reg = 0; reg < 4; ++reg) {
            int m = wm * 64 + i * 16 + q * 4 + reg;
            int u = ut * 16 + (m >> 3);
            int w = wt * 8 + (m & 7);
            if (w < u) continue;
            const float* au = a + (size_t)u * 1024;
            const float* bw = b + (size_t)w * 1024;
            unsigned short* hrow = h + ((size_t)u * 128 + w) * 1024;
#pragma unroll
            for (int j = 0; j < 4; ++j)
                hrow[nj[j]] = f2b(fmaxf(acc[i][j][reg] + au[nj[j]] + bw[nj[j]] + b1v[j], 0.f));
            if (w > u) {
                const float* aw_ = a + (size_t)w * 1024;
                const float* bu = b + (size_t)u * 1024;
                unsigned short* hrow2 = h + ((size_t)w * 128 + u) * 1024;
#pragma unroll
                for (int j = 0; j < 4; ++j)
                    hrow2[nj[j]] = f2b(fmaxf(acc[i][j][reg] + aw_[nj[j]] + bu[nj[j]] + b1v[j], 0.f));
            }
        }
    }
}

// ---------------- K5 fallback (on-the-fly product; used if ws too small) --------
__global__ __launch_bounds__(256) void k5_mfma(
    const unsigned short* __restrict__ sb, const unsigned short* __restrict__ wT,
    const float* __restrict__ a, const float* __restrict__ b,
    const float* __restrict__ b1, unsigned short* __restrict__ h) {
    __shared__ __align__(16) unsigned short Ash[128 * 32];
    __shared__ __align__(16) unsigned short Bsh[128 * 32];
    int tid = threadIdx.x;
    int u = blockIdx.y;
    int col0 = blockIdx.x * 128;
    int lane = tid & 63, wave = tid >> 6;
    int wm = wave >> 1, wn = wave & 1;
    int q = lane >> 4, l15 = lane & 15;

    floatx4 acc[4][4];
#pragma unroll
    for (int i = 0; i < 4; ++i)
#pragma unroll
        for (int j = 0; j < 4; ++j) acc[i][j] = (floatx4){0.f, 0.f, 0.f, 0.f};

    int r = tid >> 1;
    int cb = (tid & 1) * 2;
    int sw = (r >> 1) & 3;
    const unsigned short* arow = sb + (size_t)r * 2368 + cb * 8;
    const unsigned short* urow = sb + (size_t)u * 2368 + cb * 8;
    const unsigned short* brow = wT + (size_t)(col0 + r) * 2368 + cb * 8;
    unsigned short* awp0 = Ash + r * 32 + (cb ^ sw) * 8;
    unsigned short* awp1 = Ash + r * 32 + ((cb + 1) ^ sw) * 8;
    unsigned short* bwp0 = Bsh + r * 32 + (cb ^ sw) * 8;
    unsigned short* bwp1 = Bsh + r * 32 + ((cb + 1) ^ sw) * 8;

    for (int kt = 0; kt < 74; ++kt) {
        int k0 = kt * 32;
        uint4 av0 = *(const uint4*)(arow + k0);
        uint4 av1 = *(const uint4*)(arow + k0 + 8);
        uint4 uv0 = *(const uint4*)(urow + k0);
        uint4 uv1 = *(const uint4*)(urow + k0 + 8);
        uint4 bv0 = *(const uint4*)(brow + k0);
        uint4 bv1 = *(const uint4*)(brow + k0 + 8);
        __syncthreads();
        uint4 p0, p1;
        p0.x = mul2bf(av0.x, uv0.x); p0.y = mul2bf(av0.y, uv0.y);
        p0.z = mul2bf(av0.z, uv0.z); p0.w = mul2bf(av0.w, uv0.w);
        p1.x = mul2bf(av1.x, uv1.x); p1.y = mul2bf(av1.y, uv1.y);
        p1.z = mul2bf(av1.z, uv1.z); p1.w = mul2bf(av1.w, uv1.w);
        *(uint4*)awp0 = p0;
        *(uint4*)awp1 = p1;
        *(uint4*)bwp0 = bv0;
        *(uint4*)bwp1 = bv1;
        __syncthreads();
        short8 af[4], bfv[4];
#pragma unroll
        for (int i = 0; i < 4; ++i) {
            int rA = wm * 64 + i * 16 + l15;
            af[i] = *(const short8*)(Ash + rA * 32 + (q ^ ((rA >> 1) & 3)) * 8);
        }
#pragma unroll
        for (int j = 0; j < 4; ++j) {
            int rB = wn * 64 + j * 16 + l15;
            bfv[j] = *(const short8*)(Bsh + rB * 32 + (q ^ ((rB >> 1) & 3)) * 8);
        }
#pragma unroll
        for (int i = 0; i < 4; ++i)
#pragma unroll
            for (int j = 0; j < 4; ++j)
                acc[i][j] = __builtin_amdgcn_mfma_f32_16x16x32_bf16(af[i], bfv[j], acc[i][j], 0, 0, 0);
    }

    float aU[4], b1v[4];
    int nj[4];
#pragma unroll
    for (int j = 0; j < 4; ++j) {
        nj[j] = col0 + wn * 64 + j * 16 + l15;
        aU[j] = a[u * 1024 + nj[j]];
        b1v[j] = b1[nj[j]];
    }
    size_t hbase = (size_t)u * 128 * 1024;
#pragma unroll
    for (int i = 0; i < 4; ++i) {
#pragma unroll
        for (int reg = 0; reg < 4; ++reg) {
            int w = wm * 64 + i * 16 + q * 4 + reg;
            const float* brw = b + (size_t)w * 1024;
            unsigned short* hrow = h + hbase + (size_t)w * 1024;
#pragma unroll
            for (int j = 0; j < 4; ++j) {
                float v = acc[i][j][reg] + aU[j] + brw[nj[j]] + b1v[j];
                hrow[nj[j]] = f2b(fmaxf(v, 0.f));
            }
        }
    }
}

// ---------------- K6 (MFMA, XCD-swizzled, BK=64): ts += (relu(h@W2+b2))@w3 ---------------
__global__ __launch_bounds__(256) void k6_gemm(
    const unsigned short* __restrict__ h, const unsigned short* __restrict__ w2T,
    const float* __restrict__ b2, const float* __restrict__ w3,
    float* __restrict__ ts) {
    __shared__ __align__(16) unsigned short Ash[128 * 64];
    __shared__ __align__(16) unsigned short Bsh[128 * 64];
    int tid = threadIdx.x;
    int bid = blockIdx.x;
    int r8 = bid & 7, t = bid >> 3;
    int cb = t & 7, mb = r8 + 8 * (t >> 3);
    int m0 = mb * 128;
    int col0 = cb * 128;
    int lane = tid & 63, wave = tid >> 6;
    int wm = wave >> 1, wn = wave & 1;
    int q = lane >> 4, l15 = lane & 15;

    floatx4 acc[4][4];
#pragma unroll
    for (int i = 0; i < 4; ++i)
#pragma unroll
        for (int j = 0; j < 4; ++j) acc[i][j] = (floatx4){0.f, 0.f, 0.f, 0.f};

    int ci0 = wave * 2, ci1 = wave * 2 + 1;
    int p = lane & 3;
    int r0 = ci0 * 16 + (lane >> 2), r1 = ci1 * 16 + (lane >> 2);
    int c0s = p ^ ((r0 >> 1) & 3), c1s = p ^ ((r1 >> 1) & 3);
    const char* gA0 = (const char*)(h + (size_t)(m0 + r0) * 1024) + c0s * 16;
    const char* gA1 = (const char*)(h + (size_t)(m0 + r1) * 1024) + c1s * 16;
    const char* gB0 = (const char*)(w2T + (size_t)(col0 + r0) * 1024) + c0s * 16;
    const char* gB1 = (const char*)(w2T + (size_t)(col0 + r1) * 1024) + c1s * 16;
    unsigned short* lA0 = Ash + ci0 * 512;
    unsigned short* lA1 = Ash + ci1 * 512;
    unsigned short* lB0 = Bsh + ci0 * 512;
    unsigned short* lB1 = Bsh + ci1 * 512;

    for (int kt = 0; kt < 16; ++kt) {
        __syncthreads();
        GLL16(gA0, lA0);
        GLL16(gA0 + 64, lA0 + 4096);
        GLL16(gA1, lA1);
        GLL16(gA1 + 64, lA1 + 4096);
        GLL16(gB0, lB0);
        GLL16(gB0 + 64, lB0 + 4096);
        GLL16(gB1, lB1);
        GLL16(gB1 + 64, lB1 + 4096);
        gA0 += 128; gA1 += 128; gB0 += 128; gB1 += 128;
        __syncthreads();
#pragma unroll
        for (int st = 0; st < 2; ++st) {
            const unsigned short* Asub = Ash + st * 4096;
            const unsigned short* Bsub = Bsh + st * 4096;
            short8 af[4], bfv[4];
#pragma unroll
            for (int i = 0; i < 4; ++i) {
                int rA = wm * 64 + i * 16 + l15;
                af[i] = *(const short8*)(Asub + rA * 32 + (q ^ ((rA >> 1) & 3)) * 8);
            }
#pragma unroll
            for (int j = 0; j < 4; ++j) {
                int rB = wn * 64 + j * 16 + l15;
                bfv[j] = *(const short8*)(Bsub + rB * 32 + (q ^ ((rB >> 1) & 3)) * 8);
            }
#pragma unroll
            for (int i = 0; i < 4; ++i)
#pragma unroll
                for (int j = 0; j < 4; ++j)
                    acc[i][j] = __builtin_amdgcn_mfma_f32_16x16x32_bf16(af[i], bfv[j], acc[i][j], 0, 0, 0);
        }
    }

    float b2v[4], w3v[4];
    int nj[4];
#pragma unroll
    for (int j = 0; j < 4; ++j) {
        nj[j] = col0 + wn * 64 + j * 16 + l15;
        b2v[j] = b2[nj[j]];
        w3v[j] = w3[nj[j]];
    }
#pragma unroll
    for (int i = 0; i < 4; ++i) {
#pragma unroll
        for (int reg = 0; reg < 4; ++reg) {
            float s = 0.f;
#pragma unroll
            for (int j = 0; j < 4; ++j)
                s += fmaxf(acc[i][j][reg] + b2v[j], 0.f) * w3v[j];
            s += __shfl_down(s, 8, 16);
            s += __shfl_down(s, 4, 16);
            s += __shfl_down(s, 2, 16);
            s += __shfl_down(s, 1, 16);
            if (l15 == 0)
                atomicAdd(&ts[m0 + wm * 64 + i * 16 + q * 4 + reg], s);
        }
    }
}

// ---------------- K7: adaptive S_c + final loss (parallelized) ----------------
__global__ __launch_bounds__(256) void k7_final(
    const float* __restrict__ ts, const float* __restrict__ Sg,
    const float* __restrict__ m1, const float* __restrict__ b3,
    float* __restrict__ out) {
    __shared__ float rmv[1024], cmv[1024];
    __shared__ float cnt[8], m1s[128];
    __shared__ float Sc[64];
    __shared__ float mg[8][8], mgT[8][8], mc[8][8];
    int tid = threadIdx.x;
    if (tid < 128) m1s[tid] = m1[tid];
    __syncthreads();
    if (tid < 8) {
        float c = 0.f;
        for (int k = 0; k < 16; ++k) c += m1s[tid * 16 + k];
        cnt[tid] = c;
    }
    __syncthreads();
    float b3v = b3[0];
    for (int t = tid; t < 1024; t += 256) {
        int s = t >> 7, v = (t >> 4) & 7, x = t & 15;
        const float* row = ts + (size_t)(s * 16 + x) * 128 + v * 16;
        float r = 0.f;
#pragma unroll
        for (int j = 0; j < 16; ++j) r += (row[j] + b3v) * m1s[v * 16 + j];
        rmv[t] = r / cnt[v];
        float c2 = 0.f;
#pragma unroll
        for (int i = 0; i < 16; ++i)
            c2 += (ts[(size_t)(s * 16 + i) * 128 + v * 16 + x] + b3v) * m1s[s * 16 + i];
        cmv[t] = c2 / cnt[s];
    }
    __syncthreads();
    if (tid < 64) {
        int s = tid >> 3, v = tid & 7;
        float max1 = NEG_INF, max2 = NEG_INF;
        for (int i = 0; i < 16; ++i)
            if (m1s[s * 16 + i] > 0.f) max1 = fmaxf(max1, rmv[(s << 7) | (v << 4) | i]);
        for (int j = 0; j < 16; ++j)
            if (m1s[v * 16 + j] > 0.f) max2 = fmaxf(max2, cmv[(s << 7) | (v << 4) | j]);
        Sc[tid] = 0.5f * (max1 + max2);
    }
    __syncthreads();
    if (tid < 8) {
        int r = tid;
        float mx = NEG_INF;
        for (int v = 0; v < 8; ++v) mx = fmaxf(mx, Sg[r * 8 + v]);
        float sm = 0.f;
        for (int v = 0; v < 8; ++v) sm += expf(Sg[r * 8 + v] - mx);
        for (int v = 0; v < 8; ++v) mg[r][v] = expf(Sg[r * 8 + v] - mx) / sm;

        mx = NEG_INF;
        for (int v = 0; v < 8; ++v) mx = fmaxf(mx, Sc[r * 8 + v]);
        sm = 0.f;
        for (int v = 0; v < 8; ++v) sm += expf(Sc[r * 8 + v] - mx);
        for (int v = 0; v < 8; ++v) mc[r][v] = expf(Sc[r * 8 + v] - mx) / sm;

        mx = NEG_INF;
        for (int s2 = 0; s2 < 8; ++s2) mx = fmaxf(mx, Sg[s2 * 8 + r]);
        sm = 0.f;
        for (int s2 = 0; s2 < 8; ++s2) sm += expf(Sg[s2 * 8 + r] - mx);
        for (int s2 = 0; s2 < 8; ++s2) mgT[r][s2] = expf(Sg[s2 * 8 + r] - mx) / sm;
    }
    __syncthreads();
    if (tid == 0) {
        float loss = 0.f;
        for (int r = 0; r < 8; ++r) {
            float d1 = 0.f, d2 = 0.f;
            for (int v = 0; v < 8; ++v) {
                d1 += mg[r][v] * mc[r][v];
                d2 += mgT[r][v] * mc[r][v];
            }
            loss -= logf(d1) + logf(d2);
        }
        out[0] = loss / 8.f;
    }
}

extern "C" void kernel_launch(void* const* d_in, const int* in_sizes, int n_in,
                              void* d_out, int out_size, void* d_ws, size_t ws_size,
                              hipStream_t stream) {
    const float* doc   = (const float*)d_in[0];
    const float* img   = (const float*)d_in[1];
    const float* tm    = (const float*)d_in[2];
    const float* im    = (const float*)d_in[3];
    const float* se    = (const float*)d_in[4];
    const float* cont  = (const float*)d_in[5];
    const int*   width = (const int*)d_in[6];
    const float* m1    = (const float*)d_in[7];
    const float* aw1   = (const float*)d_in[8];
    const float* ab1   = (const float*)d_in[9];
    const float* aw2   = (const float*)d_in[10];
    const float* ab2   = (const float*)d_in[11];
    const float* wemb  = (const float*)d_in[12];
    const float* pw_w1 = (const float*)d_in[13];
    const float* pw_b1 = (const float*)d_in[14];
    const float* pw_w2 = (const float*)d_in[15];
    const float* pw_b2 = (const float*)d_in[16];
    const float* pw_w3 = (const float*)d_in[17];
    const float* pw_b3 = (const float*)d_in[18];
    float* out = (float*)d_out;

    char* ws = (char*)d_ws;
    float* scores           = (float*)(ws + 0);                 // 1280 f32
    float* a                = (float*)(ws + 8192);              // 128*1024 f32
    float* b                = (float*)(ws + 532480);            // 128*1024 f32
    float* Sg               = (float*)(ws + 1056768);           // 64 f32
    float* ts               = (float*)(ws + 1057024);           // 16384 f32
    unsigned short* sb      = (unsigned short*)(ws + 1122560);  // 128*2368 bf16
    unsigned short* w1cT    = (unsigned short*)(ws + 1728768);  // 1024*2368 bf16
    unsigned short* w2T     = (unsigned short*)(ws + 6578432);  // 1024*1024 bf16
    unsigned short* h       = (unsigned short*)(ws + 8675584);  // 16384*1024 bf16 (33.5 MB)
    unsigned short* P       = (unsigned short*)(ws + 42230016); // 16384*2368 bf16 (77.6 MB)
    const size_t NEED_P = 42230016ull + 16384ull * 2368ull * 2ull;
    // Overlays inside the h region (all dead before k5 writes h):
    unsigned short* contb   = (unsigned short*)(ws + 8675584);  // 1280*768 bf16
    unsigned short* aw1T    = (unsigned short*)(ws + 10641664); // 1024*768 bf16
    unsigned short* w1aT    = (unsigned short*)(ws + 12214528); // 1024*2368 bf16
    unsigned short* w1bT    = (unsigned short*)(ws + 17064192); // 1024*2368 bf16
    float* attall           = (float*)(ws + 21913856);          // 512*288 f32

    int doP = (ws_size >= NEED_P) ? 1 : 0;

    kprep<<<8880, 256, 0, stream>>>(pw_w1, pw_w2, aw1, cont, w1cT, w1aT, w1bT,
                                    w2T, aw1T, contb, ts, scores, attall, a, b);
    kmidA<<<176, 256, 0, stream>>>(contb, aw1T, ab1, aw2, scores, doc, img, attall);
    k2_assemble<<<128, 256, 0, stream>>>(se, cont, width, scores, ab2, wemb, sb);
    kmidB<<<16576, 256, 0, stream>>>(sb, P, doP, w1aT, w1bT, a, b, attall, tm, im, Sg);
    if (doP) {
        k5_sym<<<576, 256, 0, stream>>>(P, w1cT, a, b, pw_b1, h);
    } else {
        k5_mfma<<<dim3(8, 128), 256, 0, stream>>>(sb, w1cT, a, b, pw_b1, h);
    }
    k6_gemm<<<1024, 256, 0, stream>>>(h, w2T, pw_b2, pw_w3, ts);
    k7_final<<<1, 256, 0, stream>>>(ts, Sg, m1, pw_b3, out);
}

// Round 9
// 336.664 us; speedup vs baseline: 1.0846x; 1.0846x over previous
//
#include <hip/hip_runtime.h>
#include <hip/hip_bf16.h>

#define NEGV -1e10f
#define NEG_INF -3.402823466e38f

typedef __attribute__((ext_vector_type(8))) short short8;
typedef __attribute__((ext_vector_type(4))) float floatx4;

__device__ inline float bf2f(unsigned short u) {
    union { unsigned int i; float f; } c; c.i = ((unsigned int)u) << 16; return c.f;
}
__device__ inline unsigned short f2b(float f) {
    __hip_bfloat16 h = __float2bfloat16(f);
    return *reinterpret_cast<unsigned short*>(&h);
}
// product of two packed bf16 pairs -> packed bf16 pair (RNE)
__device__ inline unsigned int mul2bf(unsigned int x, unsigned int y) {
    union { unsigned int i; float f; } xl, xh, yl, yh;
    xl.i = x << 16; xh.i = x & 0xffff0000u;
    yl.i = y << 16; yh.i = y & 0xffff0000u;
    unsigned int lo = f2b(xl.f * yl.f);
    unsigned int hi = f2b(xh.f * yh.f);
    return lo | (hi << 16);
}

#define GLL16(g, l) __builtin_amdgcn_global_load_lds( \
    (const __attribute__((address_space(1))) void*)(g), \
    (__attribute__((address_space(3))) void*)(l), 16, 0, 0)

// ---------------- KPREP: fused transposes + cont->bf16 + zero-inits ----------------
__device__ void transpose_tile(const float* __restrict__ in, int ldin, int krows,
                               unsigned short* __restrict__ out, int ldout,
                               int ktile, int ntile, unsigned short (*L)[66]) {
    int t = threadIdx.x;
    int kt = ktile * 64, nt = ntile * 64;
    int nl = t & 63, g = t >> 6;
#pragma unroll
    for (int i = 0; i < 16; ++i) {
        int kl = g * 16 + i;
        int k = kt + kl;
        float v = (k < krows) ? in[(size_t)k * ldin + nt + nl] : 0.f;
        L[kl][nl] = f2b(v);
    }
    __syncthreads();
    int kl2 = t & 63;
#pragma unroll
    for (int i = 0; i < 16; ++i) {
        int nl2 = g * 16 + i;
        out[(size_t)(nt + nl2) * ldout + kt + kl2] = L[kl2][nl2];
    }
}

__global__ __launch_bounds__(256) void kprep(
    const float* __restrict__ pw_w1, const float* __restrict__ pw_w2,
    const float* __restrict__ aw1, const float* __restrict__ cont,
    unsigned short* __restrict__ w1cT, unsigned short* __restrict__ w1aT,
    unsigned short* __restrict__ w1bT, unsigned short* __restrict__ w2T,
    unsigned short* __restrict__ aw1T, unsigned short* __restrict__ contb,
    float* __restrict__ ts, float* __restrict__ scores, float* __restrict__ attall,
    float* __restrict__ a, float* __restrict__ b) {
    __shared__ unsigned short L[64][66];
    int bid = blockIdx.x;
    int tid = threadIdx.x;
    if (bid < 592) {
        transpose_tile(pw_w1 + (size_t)2 * 2324 * 1024, 1024, 2324, w1cT, 2368,
                       bid % 37, bid / 37, L);
    } else if (bid < 1184) {
        int r = bid - 592;
        transpose_tile(pw_w1, 1024, 2324, w1aT, 2368, r % 37, r / 37, L);
    } else if (bid < 1776) {
        int r = bid - 1184;
        transpose_tile(pw_w1 + (size_t)2324 * 1024, 1024, 2324, w1bT, 2368, r % 37, r / 37, L);
    } else if (bid < 2032) {
        int r = bid - 1776;
        transpose_tile(pw_w2, 1024, 1024, w2T, 1024, r % 16, r / 16, L);
    } else if (bid < 2224) {
        int r = bid - 2032;
        transpose_tile(aw1, 1024, 768, aw1T, 768, r % 12, r / 12, L);
    } else if (bid < 6064) {
        int i = (bid - 2224) * 256 + tid;
        contb[i] = f2b(cont[i]);
    } else if (bid < 8368) {
        int i = (bid - 6064) * 256 + tid;
        attall[i] = 0.f;
        if (i < 16384) ts[i] = 0.f;
        if (i < 1280) scores[i] = 0.f;
    } else {
        int i = (bid - 8368) * 256 + tid;   // < 131072
        a[i] = 0.f;
        b[i] = 0.f;
    }
}

// ---------------- KMIDA: kscore (80 blocks) + k3a (96 blocks) merged ----------------
__global__ __launch_bounds__(256) void kmidA(
    const unsigned short* __restrict__ contb, const unsigned short* __restrict__ aw1T,
    const float* __restrict__ ab1, const float* __restrict__ aw2,
    float* __restrict__ scores,
    const float* __restrict__ doc, const float* __restrict__ img,
    float* __restrict__ attall) {
    __shared__ __align__(16) unsigned short Ash[128 * 32];
    __shared__ __align__(16) unsigned short Bsh[128 * 32];
    __shared__ float As[32][132];
    __shared__ float Bs[32][100];
    int bid = blockIdx.x;
    int tid = threadIdx.x;

    if (bid < 80) {
        // ---- kscore: scores[m] += sum_n relu(contb@aw1T + ab1)[m,n]*aw2[n] ----
        int m0 = (bid >> 3) * 128;
        int col0 = (bid & 7) * 128;
        int lane = tid & 63, wave = tid >> 6;
        int wm = wave >> 1, wn = wave & 1;
        int q = lane >> 4, l15 = lane & 15;

        floatx4 acc[4][4];
#pragma unroll
        for (int i = 0; i < 4; ++i)
#pragma unroll
            for (int j = 0; j < 4; ++j) acc[i][j] = (floatx4){0.f, 0.f, 0.f, 0.f};

        int ci0 = wave * 2, ci1 = wave * 2 + 1;
        int p = lane & 3;
        int r0 = ci0 * 16 + (lane >> 2), r1 = ci1 * 16 + (lane >> 2);
        int c0s = p ^ ((r0 >> 1) & 3), c1s = p ^ ((r1 >> 1) & 3);
        const char* gA0 = (const char*)(contb + (size_t)(m0 + r0) * 768) + c0s * 16;
        const char* gA1 = (const char*)(contb + (size_t)(m0 + r1) * 768) + c1s * 16;
        const char* gB0 = (const char*)(aw1T + (size_t)(col0 + r0) * 768) + c0s * 16;
        const char* gB1 = (const char*)(aw1T + (size_t)(col0 + r1) * 768) + c1s * 16;
        unsigned short* lA0 = Ash + ci0 * 512;
        unsigned short* lA1 = Ash + ci1 * 512;
        unsigned short* lB0 = Bsh + ci0 * 512;
        unsigned short* lB1 = Bsh + ci1 * 512;

        for (int kt = 0; kt < 24; ++kt) {
            __syncthreads();
            GLL16(gA0, lA0);
            GLL16(gA1, lA1);
            GLL16(gB0, lB0);
            GLL16(gB1, lB1);
            gA0 += 64; gA1 += 64; gB0 += 64; gB1 += 64;
            __syncthreads();
            short8 af[4], bfv[4];
#pragma unroll
            for (int i = 0; i < 4; ++i) {
                int rA = wm * 64 + i * 16 + l15;
                af[i] = *(const short8*)(Ash + rA * 32 + (q ^ ((rA >> 1) & 3)) * 8);
            }
#pragma unroll
            for (int j = 0; j < 4; ++j) {
                int rB = wn * 64 + j * 16 + l15;
                bfv[j] = *(const short8*)(Bsh + rB * 32 + (q ^ ((rB >> 1) & 3)) * 8);
            }
#pragma unroll
            for (int i = 0; i < 4; ++i)
#pragma unroll
                for (int j = 0; j < 4; ++j)
                    acc[i][j] = __builtin_amdgcn_mfma_f32_16x16x32_bf16(af[i], bfv[j], acc[i][j], 0, 0, 0);
        }

        float b1v[4], w2v[4];
        int nj[4];
#pragma unroll
        for (int j = 0; j < 4; ++j) {
            nj[j] = col0 + wn * 64 + j * 16 + l15;
            b1v[j] = ab1[nj[j]];
            w2v[j] = aw2[nj[j]];
        }
#pragma unroll
        for (int i = 0; i < 4; ++i) {
#pragma unroll
            for (int reg = 0; reg < 4; ++reg) {
                float s = 0.f;
#pragma unroll
                for (int j = 0; j < 4; ++j)
                    s += fmaxf(acc[i][j][reg] + b1v[j], 0.f) * w2v[j];
                s += __shfl_down(s, 8, 16);
                s += __shfl_down(s, 4, 16);
                s += __shfl_down(s, 2, 16);
                s += __shfl_down(s, 1, 16);
                if (l15 == 0)
                    atomicAdd(&scores[m0 + wm * 64 + i * 16 + q * 4 + reg], s);
            }
        }
    } else {
        // ---- k3a: att_all[512][288] += doc @ img^T (K-chunk) ----
        int r = bid - 80;
        int n0 = (r % 3) * 96;
        int m0 = ((r / 3) & 3) * 128;
        int k0base = (r / 12) * 128;
        int tx = tid & 15, ty = tid >> 4;
        float acc[8][6];
#pragma unroll
        for (int rr = 0; rr < 8; ++rr)
#pragma unroll
            for (int c = 0; c < 6; ++c) acc[rr][c] = 0.f;

        for (int kc = 0; kc < 4; ++kc) {
            int k0 = k0base + kc * 32;
            __syncthreads();
#pragma unroll
            for (int p2 = 0; p2 < 4; ++p2) {
                int f = tid + 256 * p2;
                int mm = f >> 3, kq = (f & 7) * 4;
                float4 v = *(const float4*)&doc[(size_t)(m0 + mm) * 1024 + k0 + kq];
                As[kq + 0][mm] = v.x; As[kq + 1][mm] = v.y;
                As[kq + 2][mm] = v.z; As[kq + 3][mm] = v.w;
            }
#pragma unroll
            for (int p2 = 0; p2 < 3; ++p2) {
                int f = tid + 256 * p2;
                int nn = f >> 3, kq = (f & 7) * 4;
                float4 v = *(const float4*)&img[(size_t)(n0 + nn) * 1024 + k0 + kq];
                Bs[kq + 0][nn] = v.x; Bs[kq + 1][nn] = v.y;
                Bs[kq + 2][nn] = v.z; Bs[kq + 3][nn] = v.w;
            }
            __syncthreads();
#pragma unroll 4
            for (int k = 0; k < 32; ++k) {
                float4 a0 = *(const float4*)&As[k][ty * 8];
                float4 a1 = *(const float4*)&As[k][ty * 8 + 4];
                float2 b0 = *(const float2*)&Bs[k][tx * 6];
                float2 b1 = *(const float2*)&Bs[k][tx * 6 + 2];
                float2 b2 = *(const float2*)&Bs[k][tx * 6 + 4];
                float ar[8] = {a0.x, a0.y, a0.z, a0.w, a1.x, a1.y, a1.z, a1.w};
                float br[6] = {b0.x, b0.y, b1.x, b1.y, b2.x, b2.y};
#pragma unroll
                for (int rr = 0; rr < 8; ++rr)
#pragma unroll
                    for (int c = 0; c < 6; ++c) acc[rr][c] = fmaf(ar[rr], br[c], acc[rr][c]);
            }
        }
#pragma unroll
        for (int rr = 0; rr < 8; ++rr)
#pragma unroll
            for (int c = 0; c < 6; ++c)
                atomicAdd(&attall[(size_t)(m0 + ty * 8 + rr) * 288 + n0 + tx * 6 + c], acc[rr][c]);
    }
}

// ---------------- K2: softmax over span tokens, assemble bf16 span embeddings -------------
__global__ __launch_bounds__(256) void k2_assemble(
    const float* __restrict__ se, const float* __restrict__ cont,
    const int* __restrict__ width, const float* __restrict__ scores,
    const float* __restrict__ ab2, const float* __restrict__ wemb,
    unsigned short* __restrict__ sb) {
    int nm = blockIdx.x, tid = threadIdx.x;
    int wd = width[nm];
    float ab2v = ab2[0];
    float sc[10];
    float m = NEG_INF;
#pragma unroll
    for (int t = 0; t < 10; ++t) {
        float s = scores[nm * 10 + t] + ab2v;
        sc[t] = (t < wd) ? s : NEGV;
        m = fmaxf(m, sc[t]);
    }
    float sum = 0.f;
#pragma unroll
    for (int t = 0; t < 10; ++t) { sc[t] = expf(sc[t] - m); sum += sc[t]; }
    float inv = 1.f / sum;
#pragma unroll
    for (int t = 0; t < 10; ++t) sc[t] *= inv;
    const float* cbase = cont + (size_t)nm * 7680;
    unsigned short* srow = sb + (size_t)nm * 2368;
    for (int d = tid; d < 768; d += 256) {
        float acc = 0.f;
#pragma unroll
        for (int t = 0; t < 10; ++t) acc = fmaf(sc[t], cbase[t * 768 + d], acc);
        srow[1536 + d] = f2b(acc);
    }
    for (int idx = tid; idx < 1536; idx += 256) srow[idx] = f2b(se[(size_t)nm * 1536 + idx]);
    if (tid < 20) srow[2304 + tid] = f2b(wemb[min(wd, 4) * 20 + tid]);
    if (tid >= 20 && tid < 64) srow[2304 + tid] = 0;
}

// ---------------- KMIDB: kP2 (16384) + k4 K-split (128) + k3b (64) merged ----------------
__global__ __launch_bounds__(256) void kmidB(
    const unsigned short* __restrict__ sb, unsigned short* __restrict__ P, int doP,
    const unsigned short* __restrict__ w1aT, const unsigned short* __restrict__ w1bT,
    float* __restrict__ aout, float* __restrict__ bout,
    const float* __restrict__ attall, const float* __restrict__ tm,
    const float* __restrict__ im, float* __restrict__ Sg) {
    __shared__ __align__(16) unsigned short Ash[128 * 32];
    __shared__ __align__(16) unsigned short Bsh[128 * 32];
    __shared__ float att[64][37];
    __shared__ float tmv[64], imv[36];
    __shared__ float s1sh;
    int bid = blockIdx.x;
    int tid = threadIdx.x;

    if (bid < 16384) {
        // ---- kP2: canonical products ----
        if (!doP) return;
        int w = bid & 127, u = bid >> 7;
        if (u > w) return;
        const uint4* su = (const uint4*)(sb + (size_t)u * 2368);
        const uint4* sw = (const uint4*)(sb + (size_t)w * 2368);
        uint4* out = (uint4*)(P + ((size_t)u * 128 + w) * 2368);
        for (int i = tid; i < 296; i += 256) {
            uint4 a = su[i], b = sw[i];
            uint4 r;
            r.x = mul2bf(a.x, b.x); r.y = mul2bf(a.y, b.y);
            r.z = mul2bf(a.z, b.z); r.w = mul2bf(a.w, b.w);
            out[i] = r;
        }
    } else if (bid < 16512) {
        // ---- k4 K-split: a += sb@w1aT[kz], b += sb@w1bT[kz] (atomic fp32) ----
        int r = bid - 16384;
        int col0 = (r & 7) * 128;
        int half = (r >> 3) & 1;
        int kz = r >> 4;                          // [0,8)
        int kt0 = (74 * kz) / 8, kt1 = (74 * (kz + 1)) / 8;
        const unsigned short* wT = half ? w1bT : w1aT;
        float* outp = half ? bout : aout;
        int lane = tid & 63, wave = tid >> 6;
        int wm = wave >> 1, wn = wave & 1;
        int q = lane >> 4, l15 = lane & 15;

        floatx4 acc[4][4];
#pragma unroll
        for (int i = 0; i < 4; ++i)
#pragma unroll
            for (int j = 0; j < 4; ++j) acc[i][j] = (floatx4){0.f, 0.f, 0.f, 0.f};

        int ci0 = wave * 2, ci1 = wave * 2 + 1;
        int p = lane & 3;
        int r0 = ci0 * 16 + (lane >> 2), r1 = ci1 * 16 + (lane >> 2);
        int c0s = p ^ ((r0 >> 1) & 3), c1s = p ^ ((r1 >> 1) & 3);
        const char* gA0 = (const char*)(sb + (size_t)r0 * 2368) + c0s * 16 + kt0 * 64;
        const char* gA1 = (const char*)(sb + (size_t)r1 * 2368) + c1s * 16 + kt0 * 64;
        const char* gB0 = (const char*)(wT + (size_t)(col0 + r0) * 2368) + c0s * 16 + kt0 * 64;
        const char* gB1 = (const char*)(wT + (size_t)(col0 + r1) * 2368) + c1s * 16 + kt0 * 64;
        unsigned short* lA0 = Ash + ci0 * 512;
        unsigned short* lA1 = Ash + ci1 * 512;
        unsigned short* lB0 = Bsh + ci0 * 512;
        unsigned short* lB1 = Bsh + ci1 * 512;

        for (int kt = kt0; kt < kt1; ++kt) {
            __syncthreads();
            GLL16(gA0, lA0);
            GLL16(gA1, lA1);
            GLL16(gB0, lB0);
            GLL16(gB1, lB1);
            gA0 += 64; gA1 += 64; gB0 += 64; gB1 += 64;
            __syncthreads();
            short8 af[4], bfv[4];
#pragma unroll
            for (int i = 0; i < 4; ++i) {
                int rA = wm * 64 + i * 16 + l15;
                af[i] = *(const short8*)(Ash + rA * 32 + (q ^ ((rA >> 1) & 3)) * 8);
            }
#pragma unroll
            for (int j = 0; j < 4; ++j) {
                int rB = wn * 64 + j * 16 + l15;
                bfv[j] = *(const short8*)(Bsh + rB * 32 + (q ^ ((rB >> 1) & 3)) * 8);
            }
#pragma unroll
            for (int i = 0; i < 4; ++i)
#pragma unroll
                for (int j = 0; j < 4; ++j)
                    acc[i][j] = __builtin_amdgcn_mfma_f32_16x16x32_bf16(af[i], bfv[j], acc[i][j], 0, 0, 0);
        }

        int nj[4];
#pragma unroll
        for (int j = 0; j < 4; ++j) nj[j] = col0 + wn * 64 + j * 16 + l15;
#pragma unroll
        for (int i = 0; i < 4; ++i) {
#pragma unroll
            for (int reg = 0; reg < 4; ++reg) {
                int row = wm * 64 + i * 16 + q * 4 + reg;
#pragma unroll
                for (int j = 0; j < 4; ++j)
                    atomicAdd(&outp[(size_t)row * 1024 + nj[j]], acc[i][j][reg]);
            }
        }
    } else {
        // ---- k3b: per (s,v) mask + two softmax-reductions -> Sg ----
        int r2 = bid - 16512;
        int s = r2 >> 3, v = r2 & 7;
        if (tid < 64) tmv[tid] = tm[s * 64 + tid];
        if (tid >= 64 && tid < 100) imv[tid - 64] = im[v * 36 + (tid - 64)];
        __syncthreads();
        for (int idx = tid; idx < 2304; idx += 256) {
            int i = idx / 36, j = idx - i * 36;
            float raw = attall[(size_t)(s * 64 + i) * 288 + v * 36 + j];
            float x = raw * tmv[i] * imv[j];
            att[i][j] = (x != 0.f) ? x : NEGV;
        }
        __syncthreads();
        float part = 0.f;
        if (tid < 64) {
            int i = tid;
            float mx = NEG_INF;
            for (int j = 0; j < 36; ++j) mx = fmaxf(mx, att[i][j] * imv[j]);
            float sum = 0.f;
            for (int j = 0; j < 36; ++j) sum += expf(att[i][j] * imv[j] - mx);
            float invs = 1.f / sum;
            for (int j = 0; j < 36; ++j) {
                float aw = expf(att[i][j] * imv[j] - mx) * invs * (tmv[i] * imv[j]);
                part += aw * att[i][j];
            }
            for (int off = 32; off > 0; off >>= 1) part += __shfl_down(part, off);
            if (tid == 0) s1sh = part;
        }
        __syncthreads();
        if (tid < 64) {
            float part2 = 0.f;
            if (tid < 36) {
                int j = tid;
                float mx = NEG_INF;
                for (int i = 0; i < 64; ++i) mx = fmaxf(mx, att[i][j]);
                float sum = 0.f;
                for (int i = 0; i < 64; ++i) sum += expf(att[i][j] - mx);
                float invs = 1.f / sum;
                for (int i = 0; i < 64; ++i) {
                    float aw = expf(att[i][j] - mx) * invs * (tmv[i] * imv[j]);
                    part2 += aw * att[i][j];
                }
            }
            for (int off = 32; off > 0; off >>= 1) part2 += __shfl_down(part2, off);
            if (tid == 0) Sg[s * 8 + v] = s1sh + part2;
        }
    }
}

// ---------------- K5_SYM (MFMA, symmetric pair-tiles, XCD-swizzled, BK=32) ---------------
// BK=32 is the measured optimum: BK=64 (round 8) dropped occupancy 19->12% and
// regressed 78->113 us. Do not enlarge the K-tile on this structure.
__global__ __launch_bounds__(256) void k5_sym(
    const unsigned short* __restrict__ P, const unsigned short* __restrict__ wT,
    const float* __restrict__ a, const float* __restrict__ b,
    const float* __restrict__ b1, unsigned short* __restrict__ h) {
    __shared__ __align__(16) unsigned short Ash[128 * 32];
    __shared__ __align__(16) unsigned short Bsh[128 * 32];
    int tid = threadIdx.x;
    int bid = blockIdx.x;
    int r8 = bid & 7, t = bid >> 3;
    int c = t & 7, pt = r8 + 8 * (t >> 3);
    const int offs[9] = {0, 16, 30, 42, 52, 60, 66, 70, 72};
    int ut = 0;
#pragma unroll
    for (int k = 1; k < 8; ++k) if (pt >= offs[k]) ut = k;
    int wt = 2 * ut + (pt - offs[ut]);
    int col0 = c * 128;

    int lane = tid & 63, wave = tid >> 6;
    int wm = wave >> 1, wn = wave & 1;
    int q = lane >> 4, l15 = lane & 15;

    floatx4 acc[4][4];
#pragma unroll
    for (int i = 0; i < 4; ++i)
#pragma unroll
        for (int j = 0; j < 4; ++j) acc[i][j] = (floatx4){0.f, 0.f, 0.f, 0.f};

    int ci0 = wave * 2, ci1 = wave * 2 + 1;
    int p = lane & 3;
    int r0 = ci0 * 16 + (lane >> 2), r1 = ci1 * 16 + (lane >> 2);
    int c0s = p ^ ((r0 >> 1) & 3), c1s = p ^ ((r1 >> 1) & 3);
    size_t prow0 = (size_t)(ut * 16 + (r0 >> 3)) * 128 + (wt * 8 + (r0 & 7));
    size_t prow1 = (size_t)(ut * 16 + (r1 >> 3)) * 128 + (wt * 8 + (r1 & 7));
    const char* gA0 = (const char*)(P + prow0 * 2368) + c0s * 16;
    const char* gA1 = (const char*)(P + prow1 * 2368) + c1s * 16;
    const char* gB0 = (const char*)(wT + (size_t)(col0 + r0) * 2368) + c0s * 16;
    const char* gB1 = (const char*)(wT + (size_t)(col0 + r1) * 2368) + c1s * 16;
    unsigned short* lA0 = Ash + ci0 * 512;
    unsigned short* lA1 = Ash + ci1 * 512;
    unsigned short* lB0 = Bsh + ci0 * 512;
    unsigned short* lB1 = Bsh + ci1 * 512;

    for (int kt = 0; kt < 74; ++kt) {
        __syncthreads();
        GLL16(gA0, lA0);
        GLL16(gA1, lA1);
        GLL16(gB0, lB0);
        GLL16(gB1, lB1);
        gA0 += 64; gA1 += 64; gB0 += 64; gB1 += 64;
        __syncthreads();
        short8 af[4], bfv[4];
#pragma unroll
        for (int i = 0; i < 4; ++i) {
            int rA = wm * 64 + i * 16 + l15;
            af[i] = *(const short8*)(Ash + rA * 32 + (q ^ ((rA >> 1) & 3)) * 8);
        }
#pragma unroll
        for (int j = 0; j < 4; ++j) {
            int rB = wn * 64 + j * 16 + l15;
            bfv[j] = *(const short8*)(Bsh + rB * 32 + (q ^ ((rB >> 1) & 3)) * 8);
        }
#pragma unroll
        for (int i = 0; i < 4; ++i)
#pragma unroll
            for (int j = 0; j < 4; ++j)
                acc[i][j] = __builtin_amdgcn_mfma_f32_16x16x32_bf16(af[i], bfv[j], acc[i][j], 0, 0, 0);
    }

    float b1v[4];
    int nj[4];
#pragma unroll
    for (int j = 0; j < 4; ++j) {
        nj[j] = col0 + wn * 64 + j * 16 + l15;
        b1v[j] = b1[nj[j]];
    }
#pragma unroll
    for (int i = 0; i < 4; ++i) {
#pragma unroll
        for (int reg = 0; reg < 4; ++reg) {
            int m = wm * 64 + i * 16 + q * 4 + reg;
            int u = ut * 16 + (m >> 3);
            int w = wt * 8 + (m & 7);
            if (w < u) continue;
            const float* au = a + (size_t)u * 1024;
            const float* bw = b + (size_t)w * 1024;
            unsigned short* hrow = h + ((size_t)u * 128 + w) * 1024;
#pragma unroll
            for (int j = 0; j < 4; ++j)
                hrow[nj[j]] = f2b(fmaxf(acc[i][j][reg] + au[nj[j]] + bw[nj[j]] + b1v[j], 0.f));
            if (w > u) {
                const float* aw_ = a + (size_t)w * 1024;
                const float* bu = b + (size_t)u * 1024;
                unsigned short* hrow2 = h + ((size_t)w * 128 + u) * 1024;
#pragma unroll
                for (int j = 0; j < 4; ++j)
                    hrow2[nj[j]] = f2b(fmaxf(acc[i][j][reg] + aw_[nj[j]] + bu[nj[j]] + b1v[j], 0.f));
            }
        }
    }
}

// ---------------- K5 fallback (on-the-fly product; used if ws too small) --------
__global__ __launch_bounds__(256) void k5_mfma(
    const unsigned short* __restrict__ sb, const unsigned short* __restrict__ wT,
    const float* __restrict__ a, const float* __restrict__ b,
    const float* __restrict__ b1, unsigned short* __restrict__ h) {
    __shared__ __align__(16) unsigned short Ash[128 * 32];
    __shared__ __align__(16) unsigned short Bsh[128 * 32];
    int tid = threadIdx.x;
    int u = blockIdx.y;
    int col0 = blockIdx.x * 128;
    int lane = tid & 63, wave = tid >> 6;
    int wm = wave >> 1, wn = wave & 1;
    int q = lane >> 4, l15 = lane & 15;

    floatx4 acc[4][4];
#pragma unroll
    for (int i = 0; i < 4; ++i)
#pragma unroll
        for (int j = 0; j < 4; ++j) acc[i][j] = (floatx4){0.f, 0.f, 0.f, 0.f};

    int r = tid >> 1;
    int cb = (tid & 1) * 2;
    int sw = (r >> 1) & 3;
    const unsigned short* arow = sb + (size_t)r * 2368 + cb * 8;
    const unsigned short* urow = sb + (size_t)u * 2368 + cb * 8;
    const unsigned short* brow = wT + (size_t)(col0 + r) * 2368 + cb * 8;
    unsigned short* awp0 = Ash + r * 32 + (cb ^ sw) * 8;
    unsigned short* awp1 = Ash + r * 32 + ((cb + 1) ^ sw) * 8;
    unsigned short* bwp0 = Bsh + r * 32 + (cb ^ sw) * 8;
    unsigned short* bwp1 = Bsh + r * 32 + ((cb + 1) ^ sw) * 8;

    for (int kt = 0; kt < 74; ++kt) {
        int k0 = kt * 32;
        uint4 av0 = *(const uint4*)(arow + k0);
        uint4 av1 = *(const uint4*)(arow + k0 + 8);
        uint4 uv0 = *(const uint4*)(urow + k0);
        uint4 uv1 = *(const uint4*)(urow + k0 + 8);
        uint4 bv0 = *(const uint4*)(brow + k0);
        uint4 bv1 = *(const uint4*)(brow + k0 + 8);
        __syncthreads();
        uint4 p0, p1;
        p0.x = mul2bf(av0.x, uv0.x); p0.y = mul2bf(av0.y, uv0.y);
        p0.z = mul2bf(av0.z, uv0.z); p0.w = mul2bf(av0.w, uv0.w);
        p1.x = mul2bf(av1.x, uv1.x); p1.y = mul2bf(av1.y, uv1.y);
        p1.z = mul2bf(av1.z, uv1.z); p1.w = mul2bf(av1.w, uv1.w);
        *(uint4*)awp0 = p0;
        *(uint4*)awp1 = p1;
        *(uint4*)bwp0 = bv0;
        *(uint4*)bwp1 = bv1;
        __syncthreads();
        short8 af[4], bfv[4];
#pragma unroll
        for (int i = 0; i < 4; ++i) {
            int rA = wm * 64 + i * 16 + l15;
            af[i] = *(const short8*)(Ash + rA * 32 + (q ^ ((rA >> 1) & 3)) * 8);
        }
#pragma unroll
        for (int j = 0; j < 4; ++j) {
            int rB = wn * 64 + j * 16 + l15;
            bfv[j] = *(const short8*)(Bsh + rB * 32 + (q ^ ((rB >> 1) & 3)) * 8);
        }
#pragma unroll
        for (int i = 0; i < 4; ++i)
#pragma unroll
            for (int j = 0; j < 4; ++j)
                acc[i][j] = __builtin_amdgcn_mfma_f32_16x16x32_bf16(af[i], bfv[j], acc[i][j], 0, 0, 0);
    }

    float aU[4], b1v[4];
    int nj[4];
#pragma unroll
    for (int j = 0; j < 4; ++j) {
        nj[j] = col0 + wn * 64 + j * 16 + l15;
        aU[j] = a[u * 1024 + nj[j]];
        b1v[j] = b1[nj[j]];
    }
    size_t hbase = (size_t)u * 128 * 1024;
#pragma unroll
    for (int i = 0; i < 4; ++i) {
#pragma unroll
        for (int reg = 0; reg < 4; ++reg) {
            int w = wm * 64 + i * 16 + q * 4 + reg;
            const float* brw = b + (size_t)w * 1024;
            unsigned short* hrow = h + hbase + (size_t)w * 1024;
#pragma unroll
            for (int j = 0; j < 4; ++j) {
                float v = acc[i][j][reg] + aU[j] + brw[nj[j]] + b1v[j];
                hrow[nj[j]] = f2b(fmaxf(v, 0.f));
            }
        }
    }
}

// ---------------- K6 (MFMA, XCD-swizzled, BK=32): ts += (relu(h@W2+b2))@w3 ---------------
__global__ __launch_bounds__(256) void k6_gemm(
    const unsigned short* __restrict__ h, const unsigned short* __restrict__ w2T,
    const float* __restrict__ b2, const float* __restrict__ w3,
    float* __restrict__ ts) {
    __shared__ __align__(16) unsigned short Ash[128 * 32];
    __shared__ __align__(16) unsigned short Bsh[128 * 32];
    int tid = threadIdx.x;
    int bid = blockIdx.x;
    int r8 = bid & 7, t = bid >> 3;
    int cb = t & 7, mb = r8 + 8 * (t >> 3);
    int m0 = mb * 128;
    int col0 = cb * 128;
    int lane = tid & 63, wave = tid >> 6;
    int wm = wave >> 1, wn = wave & 1;
    int q = lane >> 4, l15 = lane & 15;

    floatx4 acc[4][4];
#pragma unroll
    for (int i = 0; i < 4; ++i)
#pragma unroll
        for (int j = 0; j < 4; ++j) acc[i][j] = (floatx4){0.f, 0.f, 0.f, 0.f};

    int ci0 = wave * 2, ci1 = wave * 2 + 1;
    int p = lane & 3;
    int r0 = ci0 * 16 + (lane >> 2), r1 = ci1 * 16 + (lane >> 2);
    int c0s = p ^ ((r0 >> 1) & 3), c1s = p ^ ((r1 >> 1) & 3);
    const char* gA0 = (const char*)(h + (size_t)(m0 + r0) * 1024) + c0s * 16;
    const char* gA1 = (const char*)(h + (size_t)(m0 + r1) * 1024) + c1s * 16;
    const char* gB0 = (const char*)(w2T + (size_t)(col0 + r0) * 1024) + c0s * 16;
    const char* gB1 = (const char*)(w2T + (size_t)(col0 + r1) * 1024) + c1s * 16;
    unsigned short* lA0 = Ash + ci0 * 512;
    unsigned short* lA1 = Ash + ci1 * 512;
    unsigned short* lB0 = Bsh + ci0 * 512;
    unsigned short* lB1 = Bsh + ci1 * 512;

    for (int kt = 0; kt < 32; ++kt) {
        __syncthreads();
        GLL16(gA0, lA0);
        GLL16(gA1, lA1);
        GLL16(gB0, lB0);
        GLL16(gB1, lB1);
        gA0 += 64; gA1 += 64; gB0 += 64; gB1 += 64;
        __syncthreads();
        short8 af[4], bfv[4];
#pragma unroll
        for (int i = 0; i < 4; ++i) {
            int rA = wm * 64 + i * 16 + l15;
            af[i] = *(const short8*)(Ash + rA * 32 + (q ^ ((rA >> 1) & 3)) * 8);
        }
#pragma unroll
        for (int j = 0; j < 4; ++j) {
            int rB = wn * 64 + j * 16 + l15;
            bfv[j] = *(const short8*)(Bsh + rB * 32 + (q ^ ((rB >> 1) & 3)) * 8);
        }
#pragma unroll
        for (int i = 0; i < 4; ++i)
#pragma unroll
            for (int j = 0; j < 4; ++j)
                acc[i][j] = __builtin_amdgcn_mfma_f32_16x16x32_bf16(af[i], bfv[j], acc[i][j], 0, 0, 0);
    }

    float b2v[4], w3v[4];
    int nj[4];
#pragma unroll
    for (int j = 0; j < 4; ++j) {
        nj[j] = col0 + wn * 64 + j * 16 + l15;
        b2v[j] = b2[nj[j]];
        w3v[j] = w3[nj[j]];
    }
#pragma unroll
    for (int i = 0; i < 4; ++i) {
#pragma unroll
        for (int reg = 0; reg < 4; ++reg) {
            float s = 0.f;
#pragma unroll
            for (int j = 0; j < 4; ++j)
                s += fmaxf(acc[i][j][reg] + b2v[j], 0.f) * w3v[j];
            s += __shfl_down(s, 8, 16);
            s += __shfl_down(s, 4, 16);
            s += __shfl_down(s, 2, 16);
            s += __shfl_down(s, 1, 16);
            if (l15 == 0)
                atomicAdd(&ts[m0 + wm * 64 + i * 16 + q * 4 + reg], s);
        }
    }
}

// ---------------- K7: adaptive S_c + final loss (parallelized) ----------------
__global__ __launch_bounds__(256) void k7_final(
    const float* __restrict__ ts, const float* __restrict__ Sg,
    const float* __restrict__ m1, const float* __restrict__ b3,
    float* __restrict__ out) {
    __shared__ float rmv[1024], cmv[1024];
    __shared__ float cnt[8], m1s[128];
    __shared__ float Sc[64];
    __shared__ float mg[8][8], mgT[8][8], mc[8][8];
    int tid = threadIdx.x;
    if (tid < 128) m1s[tid] = m1[tid];
    __syncthreads();
    if (tid < 8) {
        float c = 0.f;
        for (int k = 0; k < 16; ++k) c += m1s[tid * 16 + k];
        cnt[tid] = c;
    }
    __syncthreads();
    float b3v = b3[0];
    for (int t = tid; t < 1024; t += 256) {
        int s = t >> 7, v = (t >> 4) & 7, x = t & 15;
        const float* row = ts + (size_t)(s * 16 + x) * 128 + v * 16;
        float r = 0.f;
#pragma unroll
        for (int j = 0; j < 16; ++j) r += (row[j] + b3v) * m1s[v * 16 + j];
        rmv[t] = r / cnt[v];
        float c2 = 0.f;
#pragma unroll
        for (int i = 0; i < 16; ++i)
            c2 += (ts[(size_t)(s * 16 + i) * 128 + v * 16 + x] + b3v) * m1s[s * 16 + i];
        cmv[t] = c2 / cnt[s];
    }
    __syncthreads();
    if (tid < 64) {
        int s = tid >> 3, v = tid & 7;
        float max1 = NEG_INF, max2 = NEG_INF;
        for (int i = 0; i < 16; ++i)
            if (m1s[s * 16 + i] > 0.f) max1 = fmaxf(max1, rmv[(s << 7) | (v << 4) | i]);
        for (int j = 0; j < 16; ++j)
            if (m1s[v * 16 + j] > 0.f) max2 = fmaxf(max2, cmv[(s << 7) | (v << 4) | j]);
        Sc[tid] = 0.5f * (max1 + max2);
    }
    __syncthreads();
    if (tid < 8) {
        int r = tid;
        float mx = NEG_INF;
        for (int v = 0; v < 8; ++v) mx = fmaxf(mx, Sg[r * 8 + v]);
        float sm = 0.f;
        for (int v = 0; v < 8; ++v) sm += expf(Sg[r * 8 + v] - mx);
        for (int v = 0; v < 8; ++v) mg[r][v] = expf(Sg[r * 8 + v] - mx) / sm;

        mx = NEG_INF;
        for (int v = 0; v < 8; ++v) mx = fmaxf(mx, Sc[r * 8 + v]);
        sm = 0.f;
        for (int v = 0; v < 8; ++v) sm += expf(Sc[r * 8 + v] - mx);
        for (int v = 0; v < 8; ++v) mc[r][v] = expf(Sc[r * 8 + v] - mx) / sm;

        mx = NEG_INF;
        for (int s2 = 0; s2 < 8; ++s2) mx = fmaxf(mx, Sg[s2 * 8 + r]);
        sm = 0.f;
        for (int s2 = 0; s2 < 8; ++s2) sm += expf(Sg[s2 * 8 + r] - mx);
        for (int s2 = 0; s2 < 8; ++s2) mgT[r][s2] = expf(Sg[s2 * 8 + r] - mx) / sm;
    }
    __syncthreads();
    if (tid == 0) {
        float loss = 0.f;
        for (int r = 0; r < 8; ++r) {
            float d1 = 0.f, d2 = 0.f;
            for (int v = 0; v < 8; ++v) {
                d1 += mg[r][v] * mc[r][v];
                d2 += mgT[r][v] * mc[r][v];
            }
            loss -= logf(d1) + logf(d2);
        }
        out[0] = loss / 8.f;
    }
}

extern "C" void kernel_launch(void* const* d_in, const int* in_sizes, int n_in,
                              void* d_out, int out_size, void* d_ws, size_t ws_size,
                              hipStream_t stream) {
    const float* doc   = (const float*)d_in[0];
    const float* img   = (const float*)d_in[1];
    const float* tm    = (const float*)d_in[2];
    const float* im    = (const float*)d_in[3];
    const float* se    = (const float*)d_in[4];
    const float* cont  = (const float*)d_in[5];
    const int*   width = (const int*)d_in[6];
    const float* m1    = (const float*)d_in[7];
    const float* aw1   = (const float*)d_in[8];
    const float* ab1   = (const float*)d_in[9];
    const float* aw2   = (const float*)d_in[10];
    const float* ab2   = (const float*)d_in[11];
    const float* wemb  = (const float*)d_in[12];
    const float* pw_w1 = (const float*)d_in[13];
    const float* pw_b1 = (const float*)d_in[14];
    const float* pw_w2 = (const float*)d_in[15];
    const float* pw_b2 = (const float*)d_in[16];
    const float* pw_w3 = (const float*)d_in[17];
    const float* pw_b3 = (const float*)d_in[18];
    float* out = (float*)d_out;

    char* ws = (char*)d_ws;
    float* scores           = (float*)(ws + 0);                 // 1280 f32
    float* a                = (float*)(ws + 8192);              // 128*1024 f32
    float* b                = (float*)(ws + 532480);            // 128*1024 f32
    float* Sg               = (float*)(ws + 1056768);           // 64 f32
    float* ts               = (float*)(ws + 1057024);           // 16384 f32
    unsigned short* sb      = (unsigned short*)(ws + 1122560);  // 128*2368 bf16
    unsigned short* w1cT    = (unsigned short*)(ws + 1728768);  // 1024*2368 bf16
    unsigned short* w2T     = (unsigned short*)(ws + 6578432);  // 1024*1024 bf16
    unsigned short* h       = (unsigned short*)(ws + 8675584);  // 16384*1024 bf16 (33.5 MB)
    unsigned short* P       = (unsigned short*)(ws + 42230016); // 16384*2368 bf16 (77.6 MB)
    const size_t NEED_P = 42230016ull + 16384ull * 2368ull * 2ull;
    // Overlays inside the h region (all dead before k5 writes h):
    unsigned short* contb   = (unsigned short*)(ws + 8675584);  // 1280*768 bf16
    unsigned short* aw1T    = (unsigned short*)(ws + 10641664); // 1024*768 bf16
    unsigned short* w1aT    = (unsigned short*)(ws + 12214528); // 1024*2368 bf16
    unsigned short* w1bT    = (unsigned short*)(ws + 17064192); // 1024*2368 bf16
    float* attall           = (float*)(ws + 21913856);          // 512*288 f32

    int doP = (ws_size >= NEED_P) ? 1 : 0;

    kprep<<<8880, 256, 0, stream>>>(pw_w1, pw_w2, aw1, cont, w1cT, w1aT, w1bT,
                                    w2T, aw1T, contb, ts, scores, attall, a, b);
    kmidA<<<176, 256, 0, stream>>>(contb, aw1T, ab1, aw2, scores, doc, img, attall);
    k2_assemble<<<128, 256, 0, stream>>>(se, cont, width, scores, ab2, wemb, sb);
    kmidB<<<16576, 256, 0, stream>>>(sb, P, doP, w1aT, w1bT, a, b, attall, tm, im, Sg);
    if (doP) {
        k5_sym<<<576, 256, 0, stream>>>(P, w1cT, a, b, pw_b1, h);
    } else {
        k5_mfma<<<dim3(8, 128), 256, 0, stream>>>(sb, w1cT, a, b, pw_b1, h);
    }
    k6_gemm<<<1024, 256, 0, stream>>>(h, w2T, pw_b2, pw_w3, ts);
    k7_final<<<1, 256, 0, stream>>>(ts, Sg, m1, pw_b3, out);
}

// Round 10
// 329.484 us; speedup vs baseline: 1.1082x; 1.0218x over previous
//
#include <hip/hip_runtime.h>
#include <hip/hip_bf16.h>

#define NEGV -1e10f
#define NEG_INF -3.402823466e38f

typedef __attribute__((ext_vector_type(8))) short short8;
typedef __attribute__((ext_vector_type(4))) float floatx4;

__device__ inline float bf2f(unsigned short u) {
    union { unsigned int i; float f; } c; c.i = ((unsigned int)u) << 16; return c.f;
}
__device__ inline unsigned short f2b(float f) {
    __hip_bfloat16 h = __float2bfloat16(f);
    return *reinterpret_cast<unsigned short*>(&h);
}
// product of two packed bf16 pairs -> packed bf16 pair (RNE)
__device__ inline unsigned int mul2bf(unsigned int x, unsigned int y) {
    union { unsigned int i; float f; } xl, xh, yl, yh;
    xl.i = x << 16; xh.i = x & 0xffff0000u;
    yl.i = y << 16; yh.i = y & 0xffff0000u;
    unsigned int lo = f2b(xl.f * yl.f);
    unsigned int hi = f2b(xh.f * yh.f);
    return lo | (hi << 16);
}

#define GLL16(g, l) __builtin_amdgcn_global_load_lds( \
    (const __attribute__((address_space(1))) void*)(g), \
    (__attribute__((address_space(3))) void*)(l), 16, 0, 0)

// ---------------- KPREP: fused transposes + cont->bf16 + zero-inits (vectorized x4) -------
// regions: [0,592) w1cT | [592,1184) w1aT | [1184,1776) w1bT | [1776,2032) w2T
//          [2032,2224) aw1T | [2224,3184) contb x4 | [3184,3760) zero attall/ts/scores x4
//          [3760,3888) zero a/b x4
__device__ void transpose_tile(const float* __restrict__ in, int ldin, int krows,
                               unsigned short* __restrict__ out, int ldout,
                               int ktile, int ntile, unsigned short (*L)[66]) {
    int t = threadIdx.x;
    int kt = ktile * 64, nt = ntile * 64;
    int nl = t & 63, g = t >> 6;
#pragma unroll
    for (int i = 0; i < 16; ++i) {
        int kl = g * 16 + i;
        int k = kt + kl;
        float v = (k < krows) ? in[(size_t)k * ldin + nt + nl] : 0.f;
        L[kl][nl] = f2b(v);
    }
    __syncthreads();
    int kl2 = t & 63;
#pragma unroll
    for (int i = 0; i < 16; ++i) {
        int nl2 = g * 16 + i;
        out[(size_t)(nt + nl2) * ldout + kt + kl2] = L[kl2][nl2];
    }
}

__global__ __launch_bounds__(256) void kprep(
    const float* __restrict__ pw_w1, const float* __restrict__ pw_w2,
    const float* __restrict__ aw1, const float* __restrict__ cont,
    unsigned short* __restrict__ w1cT, unsigned short* __restrict__ w1aT,
    unsigned short* __restrict__ w1bT, unsigned short* __restrict__ w2T,
    unsigned short* __restrict__ aw1T, unsigned short* __restrict__ contb,
    float* __restrict__ ts, float* __restrict__ scores, float* __restrict__ attall,
    float* __restrict__ a, float* __restrict__ b) {
    __shared__ unsigned short L[64][66];
    int bid = blockIdx.x;
    int tid = threadIdx.x;
    if (bid < 592) {
        transpose_tile(pw_w1 + (size_t)2 * 2324 * 1024, 1024, 2324, w1cT, 2368,
                       bid % 37, bid / 37, L);
    } else if (bid < 1184) {
        int r = bid - 592;
        transpose_tile(pw_w1, 1024, 2324, w1aT, 2368, r % 37, r / 37, L);
    } else if (bid < 1776) {
        int r = bid - 1184;
        transpose_tile(pw_w1 + (size_t)2324 * 1024, 1024, 2324, w1bT, 2368, r % 37, r / 37, L);
    } else if (bid < 2032) {
        int r = bid - 1776;
        transpose_tile(pw_w2, 1024, 1024, w2T, 1024, r % 16, r / 16, L);
    } else if (bid < 2224) {
        int r = bid - 2032;
        transpose_tile(aw1, 1024, 768, aw1T, 768, r % 12, r / 12, L);
    } else if (bid < 3184) {
        // contb: 1280*768 = 983040 elems, 4 per thread, 960 blocks exactly
        int t4 = (bid - 2224) * 256 + tid;        // 0..245759
        float4 v = *(const float4*)&cont[(size_t)t4 * 4];
        ushort4 o;
        o.x = f2b(v.x); o.y = f2b(v.y); o.z = f2b(v.z); o.w = f2b(v.w);
        *(ushort4*)&contb[(size_t)t4 * 4] = o;
    } else if (bid < 3760) {
        // zero attall (589824 f) x4 -> 147456 threads; first ones also ts/scores
        int t4 = (bid - 3184) * 256 + tid;        // 0..147455
        float4 z = {0.f, 0.f, 0.f, 0.f};
        *(float4*)&attall[(size_t)t4 * 4] = z;
        if (t4 < 4096)  *(float4*)&ts[(size_t)t4 * 4] = z;      // 16384 f
        if (t4 < 320)   *(float4*)&scores[(size_t)t4 * 4] = z;  // 1280 f
    } else {
        // zero a, b (131072 f each) x4 -> 32768 threads = 128 blocks
        int t4 = (bid - 3760) * 256 + tid;        // 0..32767
        float4 z = {0.f, 0.f, 0.f, 0.f};
        *(float4*)&a[(size_t)t4 * 4] = z;
        *(float4*)&b[(size_t)t4 * 4] = z;
    }
}

// ---------------- KMIDA: kscore (80 blocks) + k3a (96 blocks) merged ----------------
__global__ __launch_bounds__(256) void kmidA(
    const unsigned short* __restrict__ contb, const unsigned short* __restrict__ aw1T,
    const float* __restrict__ ab1, const float* __restrict__ aw2,
    float* __restrict__ scores,
    const float* __restrict__ doc, const float* __restrict__ img,
    float* __restrict__ attall) {
    __shared__ __align__(16) unsigned short Ash[128 * 32];
    __shared__ __align__(16) unsigned short Bsh[128 * 32];
    __shared__ float As[32][132];
    __shared__ float Bs[32][100];
    int bid = blockIdx.x;
    int tid = threadIdx.x;

    if (bid < 80) {
        // ---- kscore: scores[m] += sum_n relu(contb@aw1T + ab1)[m,n]*aw2[n] ----
        int m0 = (bid >> 3) * 128;
        int col0 = (bid & 7) * 128;
        int lane = tid & 63, wave = tid >> 6;
        int wm = wave >> 1, wn = wave & 1;
        int q = lane >> 4, l15 = lane & 15;

        floatx4 acc[4][4];
#pragma unroll
        for (int i = 0; i < 4; ++i)
#pragma unroll
            for (int j = 0; j < 4; ++j) acc[i][j] = (floatx4){0.f, 0.f, 0.f, 0.f};

        int ci0 = wave * 2, ci1 = wave * 2 + 1;
        int p = lane & 3;
        int r0 = ci0 * 16 + (lane >> 2), r1 = ci1 * 16 + (lane >> 2);
        int c0s = p ^ ((r0 >> 1) & 3), c1s = p ^ ((r1 >> 1) & 3);
        const char* gA0 = (const char*)(contb + (size_t)(m0 + r0) * 768) + c0s * 16;
        const char* gA1 = (const char*)(contb + (size_t)(m0 + r1) * 768) + c1s * 16;
        const char* gB0 = (const char*)(aw1T + (size_t)(col0 + r0) * 768) + c0s * 16;
        const char* gB1 = (const char*)(aw1T + (size_t)(col0 + r1) * 768) + c1s * 16;
        unsigned short* lA0 = Ash + ci0 * 512;
        unsigned short* lA1 = Ash + ci1 * 512;
        unsigned short* lB0 = Bsh + ci0 * 512;
        unsigned short* lB1 = Bsh + ci1 * 512;

        for (int kt = 0; kt < 24; ++kt) {
            __syncthreads();
            GLL16(gA0, lA0);
            GLL16(gA1, lA1);
            GLL16(gB0, lB0);
            GLL16(gB1, lB1);
            gA0 += 64; gA1 += 64; gB0 += 64; gB1 += 64;
            __syncthreads();
            short8 af[4], bfv[4];
#pragma unroll
            for (int i = 0; i < 4; ++i) {
                int rA = wm * 64 + i * 16 + l15;
                af[i] = *(const short8*)(Ash + rA * 32 + (q ^ ((rA >> 1) & 3)) * 8);
            }
#pragma unroll
            for (int j = 0; j < 4; ++j) {
                int rB = wn * 64 + j * 16 + l15;
                bfv[j] = *(const short8*)(Bsh + rB * 32 + (q ^ ((rB >> 1) & 3)) * 8);
            }
#pragma unroll
            for (int i = 0; i < 4; ++i)
#pragma unroll
                for (int j = 0; j < 4; ++j)
                    acc[i][j] = __builtin_amdgcn_mfma_f32_16x16x32_bf16(af[i], bfv[j], acc[i][j], 0, 0, 0);
        }

        float b1v[4], w2v[4];
        int nj[4];
#pragma unroll
        for (int j = 0; j < 4; ++j) {
            nj[j] = col0 + wn * 64 + j * 16 + l15;
            b1v[j] = ab1[nj[j]];
            w2v[j] = aw2[nj[j]];
        }
#pragma unroll
        for (int i = 0; i < 4; ++i) {
#pragma unroll
            for (int reg = 0; reg < 4; ++reg) {
                float s = 0.f;
#pragma unroll
                for (int j = 0; j < 4; ++j)
                    s += fmaxf(acc[i][j][reg] + b1v[j], 0.f) * w2v[j];
                s += __shfl_down(s, 8, 16);
                s += __shfl_down(s, 4, 16);
                s += __shfl_down(s, 2, 16);
                s += __shfl_down(s, 1, 16);
                if (l15 == 0)
                    atomicAdd(&scores[m0 + wm * 64 + i * 16 + q * 4 + reg], s);
            }
        }
    } else {
        // ---- k3a: att_all[512][288] += doc @ img^T (K-chunk) ----
        int r = bid - 80;
        int n0 = (r % 3) * 96;
        int m0 = ((r / 3) & 3) * 128;
        int k0base = (r / 12) * 128;
        int tx = tid & 15, ty = tid >> 4;
        float acc[8][6];
#pragma unroll
        for (int rr = 0; rr < 8; ++rr)
#pragma unroll
            for (int c = 0; c < 6; ++c) acc[rr][c] = 0.f;

        for (int kc = 0; kc < 4; ++kc) {
            int k0 = k0base + kc * 32;
            __syncthreads();
#pragma unroll
            for (int p2 = 0; p2 < 4; ++p2) {
                int f = tid + 256 * p2;
                int mm = f >> 3, kq = (f & 7) * 4;
                float4 v = *(const float4*)&doc[(size_t)(m0 + mm) * 1024 + k0 + kq];
                As[kq + 0][mm] = v.x; As[kq + 1][mm] = v.y;
                As[kq + 2][mm] = v.z; As[kq + 3][mm] = v.w;
            }
#pragma unroll
            for (int p2 = 0; p2 < 3; ++p2) {
                int f = tid + 256 * p2;
                int nn = f >> 3, kq = (f & 7) * 4;
                float4 v = *(const float4*)&img[(size_t)(n0 + nn) * 1024 + k0 + kq];
                Bs[kq + 0][nn] = v.x; Bs[kq + 1][nn] = v.y;
                Bs[kq + 2][nn] = v.z; Bs[kq + 3][nn] = v.w;
            }
            __syncthreads();
#pragma unroll 4
            for (int k = 0; k < 32; ++k) {
                float4 a0 = *(const float4*)&As[k][ty * 8];
                float4 a1 = *(const float4*)&As[k][ty * 8 + 4];
                float2 b0 = *(const float2*)&Bs[k][tx * 6];
                float2 b1 = *(const float2*)&Bs[k][tx * 6 + 2];
                float2 b2 = *(const float2*)&Bs[k][tx * 6 + 4];
                float ar[8] = {a0.x, a0.y, a0.z, a0.w, a1.x, a1.y, a1.z, a1.w};
                float br[6] = {b0.x, b0.y, b1.x, b1.y, b2.x, b2.y};
#pragma unroll
                for (int rr = 0; rr < 8; ++rr)
#pragma unroll
                    for (int c = 0; c < 6; ++c) acc[rr][c] = fmaf(ar[rr], br[c], acc[rr][c]);
            }
        }
#pragma unroll
        for (int rr = 0; rr < 8; ++rr)
#pragma unroll
            for (int c = 0; c < 6; ++c)
                atomicAdd(&attall[(size_t)(m0 + ty * 8 + rr) * 288 + n0 + tx * 6 + c], acc[rr][c]);
    }
}

// ---------------- K2: softmax over span tokens, assemble bf16 span embeddings -------------
__global__ __launch_bounds__(256) void k2_assemble(
    const float* __restrict__ se, const float* __restrict__ cont,
    const int* __restrict__ width, const float* __restrict__ scores,
    const float* __restrict__ ab2, const float* __restrict__ wemb,
    unsigned short* __restrict__ sb) {
    int nm = blockIdx.x, tid = threadIdx.x;
    int wd = width[nm];
    float ab2v = ab2[0];
    float sc[10];
    float m = NEG_INF;
#pragma unroll
    for (int t = 0; t < 10; ++t) {
        float s = scores[nm * 10 + t] + ab2v;
        sc[t] = (t < wd) ? s : NEGV;
        m = fmaxf(m, sc[t]);
    }
    float sum = 0.f;
#pragma unroll
    for (int t = 0; t < 10; ++t) { sc[t] = expf(sc[t] - m); sum += sc[t]; }
    float inv = 1.f / sum;
#pragma unroll
    for (int t = 0; t < 10; ++t) sc[t] *= inv;
    const float* cbase = cont + (size_t)nm * 7680;
    unsigned short* srow = sb + (size_t)nm * 2368;
    for (int d = tid; d < 768; d += 256) {
        float acc = 0.f;
#pragma unroll
        for (int t = 0; t < 10; ++t) acc = fmaf(sc[t], cbase[t * 768 + d], acc);
        srow[1536 + d] = f2b(acc);
    }
    for (int idx = tid; idx < 1536; idx += 256) srow[idx] = f2b(se[(size_t)nm * 1536 + idx]);
    if (tid < 20) srow[2304 + tid] = f2b(wemb[min(wd, 4) * 20 + tid]);
    if (tid >= 20 && tid < 64) srow[2304 + tid] = 0;
}

// ---------------- KMIDB: compact kP2 (8256) + k4 K-split (128) + k3b (64) ----------------
// kP2 uses compact triangular indexing: t -> (u,w) with w>=u, no no-op dispatches.
__global__ __launch_bounds__(256) void kmidB(
    const unsigned short* __restrict__ sb, unsigned short* __restrict__ P, int doP,
    const unsigned short* __restrict__ w1aT, const unsigned short* __restrict__ w1bT,
    float* __restrict__ aout, float* __restrict__ bout,
    const float* __restrict__ attall, const float* __restrict__ tm,
    const float* __restrict__ im, float* __restrict__ Sg) {
    __shared__ __align__(16) unsigned short Ash[128 * 32];
    __shared__ __align__(16) unsigned short Bsh[128 * 32];
    __shared__ float att[64][37];
    __shared__ float tmv[64], imv[36];
    __shared__ float s1sh;
    int bid = blockIdx.x;
    int tid = threadIdx.x;

    if (bid < 8256) {
        // ---- kP2: canonical products, compact triangular index ----
        if (!doP) return;
        int t = bid;
        // start(u) = 128u - u(u-1)/2 ; invert via quadratic, then fix up
        int u = (int)((257.0 - sqrt(257.0 * 257.0 - 8.0 * (double)t)) * 0.5);
        if (u > 127) u = 127;
        if (u < 0) u = 0;
        while (u < 127 && (u + 1) * 128 - ((u + 1) * u) / 2 <= t) ++u;
        while (u > 0 && u * 128 - (u * (u - 1)) / 2 > t) --u;
        int w = u + (t - (u * 128 - (u * (u - 1)) / 2));
        const uint4* su = (const uint4*)(sb + (size_t)u * 2368);
        const uint4* sw = (const uint4*)(sb + (size_t)w * 2368);
        uint4* out = (uint4*)(P + ((size_t)u * 128 + w) * 2368);
        for (int i = tid; i < 296; i += 256) {
            uint4 a = su[i], b = sw[i];
            uint4 r;
            r.x = mul2bf(a.x, b.x); r.y = mul2bf(a.y, b.y);
            r.z = mul2bf(a.z, b.z); r.w = mul2bf(a.w, b.w);
            out[i] = r;
        }
    } else if (bid < 8384) {
        // ---- k4 K-split: a += sb@w1aT[kz], b += sb@w1bT[kz] (atomic fp32) ----
        int r = bid - 8256;
        int col0 = (r & 7) * 128;
        int half = (r >> 3) & 1;
        int kz = r >> 4;                          // [0,8)
        int kt0 = (74 * kz) / 8, kt1 = (74 * (kz + 1)) / 8;
        const unsigned short* wT = half ? w1bT : w1aT;
        float* outp = half ? bout : aout;
        int lane = tid & 63, wave = tid >> 6;
        int wm = wave >> 1, wn = wave & 1;
        int q = lane >> 4, l15 = lane & 15;

        floatx4 acc[4][4];
#pragma unroll
        for (int i = 0; i < 4; ++i)
#pragma unroll
            for (int j = 0; j < 4; ++j) acc[i][j] = (floatx4){0.f, 0.f, 0.f, 0.f};

        int ci0 = wave * 2, ci1 = wave * 2 + 1;
        int p = lane & 3;
        int r0 = ci0 * 16 + (lane >> 2), r1 = ci1 * 16 + (lane >> 2);
        int c0s = p ^ ((r0 >> 1) & 3), c1s = p ^ ((r1 >> 1) & 3);
        const char* gA0 = (const char*)(sb + (size_t)r0 * 2368) + c0s * 16 + kt0 * 64;
        const char* gA1 = (const char*)(sb + (size_t)r1 * 2368) + c1s * 16 + kt0 * 64;
        const char* gB0 = (const char*)(wT + (size_t)(col0 + r0) * 2368) + c0s * 16 + kt0 * 64;
        const char* gB1 = (const char*)(wT + (size_t)(col0 + r1) * 2368) + c1s * 16 + kt0 * 64;
        unsigned short* lA0 = Ash + ci0 * 512;
        unsigned short* lA1 = Ash + ci1 * 512;
        unsigned short* lB0 = Bsh + ci0 * 512;
        unsigned short* lB1 = Bsh + ci1 * 512;

        for (int kt = kt0; kt < kt1; ++kt) {
            __syncthreads();
            GLL16(gA0, lA0);
            GLL16(gA1, lA1);
            GLL16(gB0, lB0);
            GLL16(gB1, lB1);
            gA0 += 64; gA1 += 64; gB0 += 64; gB1 += 64;
            __syncthreads();
            short8 af[4], bfv[4];
#pragma unroll
            for (int i = 0; i < 4; ++i) {
                int rA = wm * 64 + i * 16 + l15;
                af[i] = *(const short8*)(Ash + rA * 32 + (q ^ ((rA >> 1) & 3)) * 8);
            }
#pragma unroll
            for (int j = 0; j < 4; ++j) {
                int rB = wn * 64 + j * 16 + l15;
                bfv[j] = *(const short8*)(Bsh + rB * 32 + (q ^ ((rB >> 1) & 3)) * 8);
            }
#pragma unroll
            for (int i = 0; i < 4; ++i)
#pragma unroll
                for (int j = 0; j < 4; ++j)
                    acc[i][j] = __builtin_amdgcn_mfma_f32_16x16x32_bf16(af[i], bfv[j], acc[i][j], 0, 0, 0);
        }

        int nj[4];
#pragma unroll
        for (int j = 0; j < 4; ++j) nj[j] = col0 + wn * 64 + j * 16 + l15;
#pragma unroll
        for (int i = 0; i < 4; ++i) {
#pragma unroll
            for (int reg = 0; reg < 4; ++reg) {
                int row = wm * 64 + i * 16 + q * 4 + reg;
#pragma unroll
                for (int j = 0; j < 4; ++j)
                    atomicAdd(&outp[(size_t)row * 1024 + nj[j]], acc[i][j][reg]);
            }
        }
    } else {
        // ---- k3b: per (s,v) mask + two softmax-reductions -> Sg ----
        int r2 = bid - 8384;
        int s = r2 >> 3, v = r2 & 7;
        if (tid < 64) tmv[tid] = tm[s * 64 + tid];
        if (tid >= 64 && tid < 100) imv[tid - 64] = im[v * 36 + (tid - 64)];
        __syncthreads();
        for (int idx = tid; idx < 2304; idx += 256) {
            int i = idx / 36, j = idx - i * 36;
            float raw = attall[(size_t)(s * 64 + i) * 288 + v * 36 + j];
            float x = raw * tmv[i] * imv[j];
            att[i][j] = (x != 0.f) ? x : NEGV;
        }
        __syncthreads();
        float part = 0.f;
        if (tid < 64) {
            int i = tid;
            float mx = NEG_INF;
            for (int j = 0; j < 36; ++j) mx = fmaxf(mx, att[i][j] * imv[j]);
            float sum = 0.f;
            for (int j = 0; j < 36; ++j) sum += expf(att[i][j] * imv[j] - mx);
            float invs = 1.f / sum;
            for (int j = 0; j < 36; ++j) {
                float aw = expf(att[i][j] * imv[j] - mx) * invs * (tmv[i] * imv[j]);
                part += aw * att[i][j];
            }
            for (int off = 32; off > 0; off >>= 1) part += __shfl_down(part, off);
            if (tid == 0) s1sh = part;
        }
        __syncthreads();
        if (tid < 64) {
            float part2 = 0.f;
            if (tid < 36) {
                int j = tid;
                float mx = NEG_INF;
                for (int i = 0; i < 64; ++i) mx = fmaxf(mx, att[i][j]);
                float sum = 0.f;
                for (int i = 0; i < 64; ++i) sum += expf(att[i][j] - mx);
                float invs = 1.f / sum;
                for (int i = 0; i < 64; ++i) {
                    float aw = expf(att[i][j] - mx) * invs * (tmv[i] * imv[j]);
                    part2 += aw * att[i][j];
                }
            }
            for (int off = 32; off > 0; off >>= 1) part2 += __shfl_down(part2, off);
            if (tid == 0) Sg[s * 8 + v] = s1sh + part2;
        }
    }
}

// ---------------- K5_SYM (MFMA, symmetric pair-tiles, XCD-swizzled, BK=32) ---------------
// BK=32 is the measured optimum: BK=64 (round 8) dropped occupancy 19->12% and
// regressed 78->113 us. Do not enlarge the K-tile on this structure.
__global__ __launch_bounds__(256) void k5_sym(
    const unsigned short* __restrict__ P, const unsigned short* __restrict__ wT,
    const float* __restrict__ a, const float* __restrict__ b,
    const float* __restrict__ b1, unsigned short* __restrict__ h) {
    __shared__ __align__(16) unsigned short Ash[128 * 32];
    __shared__ __align__(16) unsigned short Bsh[128 * 32];
    int tid = threadIdx.x;
    int bid = blockIdx.x;
    int r8 = bid & 7, t = bid >> 3;
    int c = t & 7, pt = r8 + 8 * (t >> 3);
    const int offs[9] = {0, 16, 30, 42, 52, 60, 66, 70, 72};
    int ut = 0;
#pragma unroll
    for (int k = 1; k < 8; ++k) if (pt >= offs[k]) ut = k;
    int wt = 2 * ut + (pt - offs[ut]);
    int col0 = c * 128;

    int lane = tid & 63, wave = tid >> 6;
    int wm = wave >> 1, wn = wave & 1;
    int q = lane >> 4, l15 = lane & 15;

    floatx4 acc[4][4];
#pragma unroll
    for (int i = 0; i < 4; ++i)
#pragma unroll
        for (int j = 0; j < 4; ++j) acc[i][j] = (floatx4){0.f, 0.f, 0.f, 0.f};

    int ci0 = wave * 2, ci1 = wave * 2 + 1;
    int p = lane & 3;
    int r0 = ci0 * 16 + (lane >> 2), r1 = ci1 * 16 + (lane >> 2);
    int c0s = p ^ ((r0 >> 1) & 3), c1s = p ^ ((r1 >> 1) & 3);
    size_t prow0 = (size_t)(ut * 16 + (r0 >> 3)) * 128 + (wt * 8 + (r0 & 7));
    size_t prow1 = (size_t)(ut * 16 + (r1 >> 3)) * 128 + (wt * 8 + (r1 & 7));
    const char* gA0 = (const char*)(P + prow0 * 2368) + c0s * 16;
    const char* gA1 = (const char*)(P + prow1 * 2368) + c1s * 16;
    const char* gB0 = (const char*)(wT + (size_t)(col0 + r0) * 2368) + c0s * 16;
    const char* gB1 = (const char*)(wT + (size_t)(col0 + r1) * 2368) + c1s * 16;
    unsigned short* lA0 = Ash + ci0 * 512;
    unsigned short* lA1 = Ash + ci1 * 512;
    unsigned short* lB0 = Bsh + ci0 * 512;
    unsigned short* lB1 = Bsh + ci1 * 512;

    for (int kt = 0; kt < 74; ++kt) {
        __syncthreads();
        GLL16(gA0, lA0);
        GLL16(gA1, lA1);
        GLL16(gB0, lB0);
        GLL16(gB1, lB1);
        gA0 += 64; gA1 += 64; gB0 += 64; gB1 += 64;
        __syncthreads();
        short8 af[4], bfv[4];
#pragma unroll
        for (int i = 0; i < 4; ++i) {
            int rA = wm * 64 + i * 16 + l15;
            af[i] = *(const short8*)(Ash + rA * 32 + (q ^ ((rA >> 1) & 3)) * 8);
        }
#pragma unroll
        for (int j = 0; j < 4; ++j) {
            int rB = wn * 64 + j * 16 + l15;
            bfv[j] = *(const short8*)(Bsh + rB * 32 + (q ^ ((rB >> 1) & 3)) * 8);
        }
#pragma unroll
        for (int i = 0; i < 4; ++i)
#pragma unroll
            for (int j = 0; j < 4; ++j)
                acc[i][j] = __builtin_amdgcn_mfma_f32_16x16x32_bf16(af[i], bfv[j], acc[i][j], 0, 0, 0);
    }

    float b1v[4];
    int nj[4];
#pragma unroll
    for (int j = 0; j < 4; ++j) {
        nj[j] = col0 + wn * 64 + j * 16 + l15;
        b1v[j] = b1[nj[j]];
    }
#pragma unroll
    for (int i = 0; i < 4; ++i) {
#pragma unroll
        for (int reg = 0; reg < 4; ++reg) {
            int m = wm * 64 + i * 16 + q * 4 + reg;
            int u = ut * 16 + (m >> 3);
            int w = wt * 8 + (m & 7);
            if (w < u) continue;
            const float* au = a + (size_t)u * 1024;
            const float* bw = b + (size_t)w * 1024;
            unsigned short* hrow = h + ((size_t)u * 128 + w) * 1024;
#pragma unroll
            for (int j = 0; j < 4; ++j)
                hrow[nj[j]] = f2b(fmaxf(acc[i][j][reg] + au[nj[j]] + bw[nj[j]] + b1v[j], 0.f));
            if (w > u) {
                const float* aw_ = a + (size_t)w * 1024;
                const float* bu = b + (size_t)u * 1024;
                unsigned short* hrow2 = h + ((size_t)w * 128 + u) * 1024;
#pragma unroll
                for (int j = 0; j < 4; ++j)
                    hrow2[nj[j]] = f2b(fmaxf(acc[i][j][reg] + aw_[nj[j]] + bu[nj[j]] + b1v[j], 0.f));
            }
        }
    }
}

// ---------------- K5 fallback (on-the-fly product; used if ws too small) --------
__global__ __launch_bounds__(256) void k5_mfma(
    const unsigned short* __restrict__ sb, const unsigned short* __restrict__ wT,
    const float* __restrict__ a, const float* __restrict__ b,
    const float* __restrict__ b1, unsigned short* __restrict__ h) {
    __shared__ __align__(16) unsigned short Ash[128 * 32];
    __shared__ __align__(16) unsigned short Bsh[128 * 32];
    int tid = threadIdx.x;
    int u = blockIdx.y;
    int col0 = blockIdx.x * 128;
    int lane = tid & 63, wave = tid >> 6;
    int wm = wave >> 1, wn = wave & 1;
    int q = lane >> 4, l15 = lane & 15;

    floatx4 acc[4][4];
#pragma unroll
    for (int i = 0; i < 4; ++i)
#pragma unroll
        for (int j = 0; j < 4; ++j) acc[i][j] = (floatx4){0.f, 0.f, 0.f, 0.f};

    int r = tid >> 1;
    int cb = (tid & 1) * 2;
    int sw = (r >> 1) & 3;
    const unsigned short* arow = sb + (size_t)r * 2368 + cb * 8;
    const unsigned short* urow = sb + (size_t)u * 2368 + cb * 8;
    const unsigned short* brow = wT + (size_t)(col0 + r) * 2368 + cb * 8;
    unsigned short* awp0 = Ash + r * 32 + (cb ^ sw) * 8;
    unsigned short* awp1 = Ash + r * 32 + ((cb + 1) ^ sw) * 8;
    unsigned short* bwp0 = Bsh + r * 32 + (cb ^ sw) * 8;
    unsigned short* bwp1 = Bsh + r * 32 + ((cb + 1) ^ sw) * 8;

    for (int kt = 0; kt < 74; ++kt) {
        int k0 = kt * 32;
        uint4 av0 = *(const uint4*)(arow + k0);
        uint4 av1 = *(const uint4*)(arow + k0 + 8);
        uint4 uv0 = *(const uint4*)(urow + k0);
        uint4 uv1 = *(const uint4*)(urow + k0 + 8);
        uint4 bv0 = *(const uint4*)(brow + k0);
        uint4 bv1 = *(const uint4*)(brow + k0 + 8);
        __syncthreads();
        uint4 p0, p1;
        p0.x = mul2bf(av0.x, uv0.x); p0.y = mul2bf(av0.y, uv0.y);
        p0.z = mul2bf(av0.z, uv0.z); p0.w = mul2bf(av0.w, uv0.w);
        p1.x = mul2bf(av1.x, uv1.x); p1.y = mul2bf(av1.y, uv1.y);
        p1.z = mul2bf(av1.z, uv1.z); p1.w = mul2bf(av1.w, uv1.w);
        *(uint4*)awp0 = p0;
        *(uint4*)awp1 = p1;
        *(uint4*)bwp0 = bv0;
        *(uint4*)bwp1 = bv1;
        __syncthreads();
        short8 af[4], bfv[4];
#pragma unroll
        for (int i = 0; i < 4; ++i) {
            int rA = wm * 64 + i * 16 + l15;
            af[i] = *(const short8*)(Ash + rA * 32 + (q ^ ((rA >> 1) & 3)) * 8);
        }
#pragma unroll
        for (int j = 0; j < 4; ++j) {
            int rB = wn * 64 + j * 16 + l15;
            bfv[j] = *(const short8*)(Bsh + rB * 32 + (q ^ ((rB >> 1) & 3)) * 8);
        }
#pragma unroll
        for (int i = 0; i < 4; ++i)
#pragma unroll
            for (int j = 0; j < 4; ++j)
                acc[i][j] = __builtin_amdgcn_mfma_f32_16x16x32_bf16(af[i], bfv[j], acc[i][j], 0, 0, 0);
    }

    float aU[4], b1v[4];
    int nj[4];
#pragma unroll
    for (int j = 0; j < 4; ++j) {
        nj[j] = col0 + wn * 64 + j * 16 + l15;
        aU[j] = a[u * 1024 + nj[j]];
        b1v[j] = b1[nj[j]];
    }
    size_t hbase = (size_t)u * 128 * 1024;
#pragma unroll
    for (int i = 0; i < 4; ++i) {
#pragma unroll
        for (int reg = 0; reg < 4; ++reg) {
            int w = wm * 64 + i * 16 + q * 4 + reg;
            const float* brw = b + (size_t)w * 1024;
            unsigned short* hrow = h + hbase + (size_t)w * 1024;
#pragma unroll
            for (int j = 0; j < 4; ++j) {
                float v = acc[i][j][reg] + aU[j] + brw[nj[j]] + b1v[j];
                hrow[nj[j]] = f2b(fmaxf(v, 0.f));
            }
        }
    }
}

// ---------------- K6 (MFMA, XCD-swizzled, BK=32): ts += (relu(h@W2+b2))@w3 ---------------
__global__ __launch_bounds__(256) void k6_gemm(
    const unsigned short* __restrict__ h, const unsigned short* __restrict__ w2T,
    const float* __restrict__ b2, const float* __restrict__ w3,
    float* __restrict__ ts) {
    __shared__ __align__(16) unsigned short Ash[128 * 32];
    __shared__ __align__(16) unsigned short Bsh[128 * 32];
    int tid = threadIdx.x;
    int bid = blockIdx.x;
    int r8 = bid & 7, t = bid >> 3;
    int cb = t & 7, mb = r8 + 8 * (t >> 3);
    int m0 = mb * 128;
    int col0 = cb * 128;
    int lane = tid & 63, wave = tid >> 6;
    int wm = wave >> 1, wn = wave & 1;
    int q = lane >> 4, l15 = lane & 15;

    floatx4 acc[4][4];
#pragma unroll
    for (int i = 0; i < 4; ++i)
#pragma unroll
        for (int j = 0; j < 4; ++j) acc[i][j] = (floatx4){0.f, 0.f, 0.f, 0.f};

    int ci0 = wave * 2, ci1 = wave * 2 + 1;
    int p = lane & 3;
    int r0 = ci0 * 16 + (lane >> 2), r1 = ci1 * 16 + (lane >> 2);
    int c0s = p ^ ((r0 >> 1) & 3), c1s = p ^ ((r1 >> 1) & 3);
    const char* gA0 = (const char*)(h + (size_t)(m0 + r0) * 1024) + c0s * 16;
    const char* gA1 = (const char*)(h + (size_t)(m0 + r1) * 1024) + c1s * 16;
    const char* gB0 = (const char*)(w2T + (size_t)(col0 + r0) * 1024) + c0s * 16;
    const char* gB1 = (const char*)(w2T + (size_t)(col0 + r1) * 1024) + c1s * 16;
    unsigned short* lA0 = Ash + ci0 * 512;
    unsigned short* lA1 = Ash + ci1 * 512;
    unsigned short* lB0 = Bsh + ci0 * 512;
    unsigned short* lB1 = Bsh + ci1 * 512;

    for (int kt = 0; kt < 32; ++kt) {
        __syncthreads();
        GLL16(gA0, lA0);
        GLL16(gA1, lA1);
        GLL16(gB0, lB0);
        GLL16(gB1, lB1);
        gA0 += 64; gA1 += 64; gB0 += 64; gB1 += 64;
        __syncthreads();
        short8 af[4], bfv[4];
#pragma unroll
        for (int i = 0; i < 4; ++i) {
            int rA = wm * 64 + i * 16 + l15;
            af[i] = *(const short8*)(Ash + rA * 32 + (q ^ ((rA >> 1) & 3)) * 8);
        }
#pragma unroll
        for (int j = 0; j < 4; ++j) {
            int rB = wn * 64 + j * 16 + l15;
            bfv[j] = *(const short8*)(Bsh + rB * 32 + (q ^ ((rB >> 1) & 3)) * 8);
        }
#pragma unroll
        for (int i = 0; i < 4; ++i)
#pragma unroll
            for (int j = 0; j < 4; ++j)
                acc[i][j] = __builtin_amdgcn_mfma_f32_16x16x32_bf16(af[i], bfv[j], acc[i][j], 0, 0, 0);
    }

    float b2v[4], w3v[4];
    int nj[4];
#pragma unroll
    for (int j = 0; j < 4; ++j) {
        nj[j] = col0 + wn * 64 + j * 16 + l15;
        b2v[j] = b2[nj[j]];
        w3v[j] = w3[nj[j]];
    }
#pragma unroll
    for (int i = 0; i < 4; ++i) {
#pragma unroll
        for (int reg = 0; reg < 4; ++reg) {
            float s = 0.f;
#pragma unroll
            for (int j = 0; j < 4; ++j)
                s += fmaxf(acc[i][j][reg] + b2v[j], 0.f) * w3v[j];
            s += __shfl_down(s, 8, 16);
            s += __shfl_down(s, 4, 16);
            s += __shfl_down(s, 2, 16);
            s += __shfl_down(s, 1, 16);
            if (l15 == 0)
                atomicAdd(&ts[m0 + wm * 64 + i * 16 + q * 4 + reg], s);
        }
    }
}

// ---------------- K7: adaptive S_c + final loss (parallelized) ----------------
__global__ __launch_bounds__(256) void k7_final(
    const float* __restrict__ ts, const float* __restrict__ Sg,
    const float* __restrict__ m1, const float* __restrict__ b3,
    float* __restrict__ out) {
    __shared__ float rmv[1024], cmv[1024];
    __shared__ float cnt[8], m1s[128];
    __shared__ float Sc[64];
    __shared__ float mg[8][8], mgT[8][8], mc[8][8];
    int tid = threadIdx.x;
    if (tid < 128) m1s[tid] = m1[tid];
    __syncthreads();
    if (tid < 8) {
        float c = 0.f;
        for (int k = 0; k < 16; ++k) c += m1s[tid * 16 + k];
        cnt[tid] = c;
    }
    __syncthreads();
    float b3v = b3[0];
    for (int t = tid; t < 1024; t += 256) {
        int s = t >> 7, v = (t >> 4) & 7, x = t & 15;
        const float* row = ts + (size_t)(s * 16 + x) * 128 + v * 16;
        float r = 0.f;
#pragma unroll
        for (int j = 0; j < 16; ++j) r += (row[j] + b3v) * m1s[v * 16 + j];
        rmv[t] = r / cnt[v];
        float c2 = 0.f;
#pragma unroll
        for (int i = 0; i < 16; ++i)
            c2 += (ts[(size_t)(s * 16 + i) * 128 + v * 16 + x] + b3v) * m1s[s * 16 + i];
        cmv[t] = c2 / cnt[s];
    }
    __syncthreads();
    if (tid < 64) {
        int s = tid >> 3, v = tid & 7;
        float max1 = NEG_INF, max2 = NEG_INF;
        for (int i = 0; i < 16; ++i)
            if (m1s[s * 16 + i] > 0.f) max1 = fmaxf(max1, rmv[(s << 7) | (v << 4) | i]);
        for (int j = 0; j < 16; ++j)
            if (m1s[v * 16 + j] > 0.f) max2 = fmaxf(max2, cmv[(s << 7) | (v << 4) | j]);
        Sc[tid] = 0.5f * (max1 + max2);
    }
    __syncthreads();
    if (tid < 8) {
        int r = tid;
        float mx = NEG_INF;
        for (int v = 0; v < 8; ++v) mx = fmaxf(mx, Sg[r * 8 + v]);
        float sm = 0.f;
        for (int v = 0; v < 8; ++v) sm += expf(Sg[r * 8 + v] - mx);
        for (int v = 0; v < 8; ++v) mg[r][v] = expf(Sg[r * 8 + v] - mx) / sm;

        mx = NEG_INF;
        for (int v = 0; v < 8; ++v) mx = fmaxf(mx, Sc[r * 8 + v]);
        sm = 0.f;
        for (int v = 0; v < 8; ++v) sm += expf(Sc[r * 8 + v] - mx);
        for (int v = 0; v < 8; ++v) mc[r][v] = expf(Sc[r * 8 + v] - mx) / sm;

        mx = NEG_INF;
        for (int s2 = 0; s2 < 8; ++s2) mx = fmaxf(mx, Sg[s2 * 8 + r]);
        sm = 0.f;
        for (int s2 = 0; s2 < 8; ++s2) sm += expf(Sg[s2 * 8 + r] - mx);
        for (int s2 = 0; s2 < 8; ++s2) mgT[r][s2] = expf(Sg[s2 * 8 + r] - mx) / sm;
    }
    __syncthreads();
    if (tid == 0) {
        float loss = 0.f;
        for (int r = 0; r < 8; ++r) {
            float d1 = 0.f, d2 = 0.f;
            for (int v = 0; v < 8; ++v) {
                d1 += mg[r][v] * mc[r][v];
                d2 += mgT[r][v] * mc[r][v];
            }
            loss -= logf(d1) + logf(d2);
        }
        out[0] = loss / 8.f;
    }
}

extern "C" void kernel_launch(void* const* d_in, const int* in_sizes, int n_in,
                              void* d_out, int out_size, void* d_ws, size_t ws_size,
                              hipStream_t stream) {
    const float* doc   = (const float*)d_in[0];
    const float* img   = (const float*)d_in[1];
    const float* tm    = (const float*)d_in[2];
    const float* im    = (const float*)d_in[3];
    const float* se    = (const float*)d_in[4];
    const float* cont  = (const float*)d_in[5];
    const int*   width = (const int*)d_in[6];
    const float* m1    = (const float*)d_in[7];
    const float* aw1   = (const float*)d_in[8];
    const float* ab1   = (const float*)d_in[9];
    const float* aw2   = (const float*)d_in[10];
    const float* ab2   = (const float*)d_in[11];
    const float* wemb  = (const float*)d_in[12];
    const float* pw_w1 = (const float*)d_in[13];
    const float* pw_b1 = (const float*)d_in[14];
    const float* pw_w2 = (const float*)d_in[15];
    const float* pw_b2 = (const float*)d_in[16];
    const float* pw_w3 = (const float*)d_in[17];
    const float* pw_b3 = (const float*)d_in[18];
    float* out = (float*)d_out;

    char* ws = (char*)d_ws;
    float* scores           = (float*)(ws + 0);                 // 1280 f32
    float* a                = (float*)(ws + 8192);              // 128*1024 f32
    float* b                = (float*)(ws + 532480);            // 128*1024 f32
    float* Sg               = (float*)(ws + 1056768);           // 64 f32
    float* ts               = (float*)(ws + 1057024);           // 16384 f32
    unsigned short* sb      = (unsigned short*)(ws + 1122560);  // 128*2368 bf16
    unsigned short* w1cT    = (unsigned short*)(ws + 1728768);  // 1024*2368 bf16
    unsigned short* w2T     = (unsigned short*)(ws + 6578432);  // 1024*1024 bf16
    unsigned short* h       = (unsigned short*)(ws + 8675584);  // 16384*1024 bf16 (33.5 MB)
    unsigned short* P       = (unsigned short*)(ws + 42230016); // 16384*2368 bf16 (77.6 MB)
    const size_t NEED_P = 42230016ull + 16384ull * 2368ull * 2ull;
    // Overlays inside the h region (all dead before k5 writes h):
    unsigned short* contb   = (unsigned short*)(ws + 8675584);  // 1280*768 bf16
    unsigned short* aw1T    = (unsigned short*)(ws + 10641664); // 1024*768 bf16
    unsigned short* w1aT    = (unsigned short*)(ws + 12214528); // 1024*2368 bf16
    unsigned short* w1bT    = (unsigned short*)(ws + 17064192); // 1024*2368 bf16
    float* attall           = (float*)(ws + 21913856);          // 512*288 f32

    int doP = (ws_size >= NEED_P) ? 1 : 0;

    kprep<<<3888, 256, 0, stream>>>(pw_w1, pw_w2, aw1, cont, w1cT, w1aT, w1bT,
                                    w2T, aw1T, contb, ts, scores, attall, a, b);
    kmidA<<<176, 256, 0, stream>>>(contb, aw1T, ab1, aw2, scores, doc, img, attall);
    k2_assemble<<<128, 256, 0, stream>>>(se, cont, width, scores, ab2, wemb, sb);
    kmidB<<<8448, 256, 0, stream>>>(sb, P, doP, w1aT, w1bT, a, b, attall, tm, im, Sg);
    if (doP) {
        k5_sym<<<576, 256, 0, stream>>>(P, w1cT, a, b, pw_b1, h);
    } else {
        k5_mfma<<<dim3(8, 128), 256, 0, stream>>>(sb, w1cT, a, b, pw_b1, h);
    }
    k6_gemm<<<1024, 256, 0, stream>>>(h, w2T, pw_b2, pw_w3, ts);
    k7_final<<<1, 256, 0, stream>>>(ts, Sg, m1, pw_b3, out);
}